// Round 10
// baseline (1280.025 us; speedup 1.0000x reference)
//
#include <hip/hip_runtime.h>
#include <math.h>

#define BB 8
#define NN 2048
#define PP 64
#define KK 32
#define DD 384
#define DEPTH 12
#define DI 768
#define DS 16
#define DCONV 4
#define DTR 24
#define NC 40
#define LL 128  // 2*PP
#define XROW (DTR + 2 * DS)  // 56
#define NR (BB * LL)         // 1024
#define XPARTS 6             // xdbl split-K partials (fused into xz blocks, K=128 each)

using bf16x8 = __attribute__((ext_vector_type(8))) short;
using floatx4 = __attribute__((ext_vector_type(4))) float;

// ---------------------------------------------------------------- helpers
__device__ __forceinline__ float gelu_exact(float x) {
    return 0.5f * x * (1.0f + erff(x * 0.70710678118654752440f));
}
__device__ __forceinline__ float siluf(float x) {
    return x / (1.0f + expf(-x));
}
__device__ __forceinline__ unsigned short f2bf(float f) {
    unsigned u = __float_as_uint(f);
    u += 0x7fffu + ((u >> 16) & 1u);   // round-to-nearest-even
    return (unsigned short)(u >> 16);
}
__device__ __forceinline__ float bf2f(short s) {
    return __uint_as_float(((unsigned)(unsigned short)s) << 16);
}
__device__ __forceinline__ unsigned spread_bits(unsigned v) {
    v &= 1023u;
    v = (v | (v << 16)) & 50331903u;
    v = (v | (v << 8)) & 50393103u;
    v = (v | (v << 4)) & 51130563u;
    v = (v | (v << 2)) & 153391689u;
    return v;
}

// ---------------------------------------------------------------- one-shot weight conversions (all four)
__global__ void k_cvt(const float* __restrict__ in_w, const float* __restrict__ out_w,
                      const float* __restrict__ pe_w3, const float* __restrict__ xp,
                      unsigned short* __restrict__ inwbf, unsigned short* __restrict__ owbf,
                      unsigned short* __restrict__ w3bf, unsigned short* __restrict__ xpbf)
{
    int idx = blockIdx.x * 256 + threadIdx.x;
    const int n1 = DEPTH * 2 * DI * DD;
    const int n2 = DEPTH * DD * DI;
    const int n3 = DD * 128;
    const int n4 = DEPTH * 64 * DI;
    if (idx < n1) { inwbf[idx] = f2bf(in_w[idx]); return; }
    idx -= n1;
    if (idx < n2) { owbf[idx] = f2bf(out_w[idx]); return; }
    idx -= n2;
    if (idx < n3) { w3bf[idx] = f2bf(pe_w3[idx]); return; }
    idx -= n3;
    if (idx < n4) {
        int i = idx / (64 * DI);
        int rem = idx - i * 64 * DI;
        int n = rem / DI, k = rem % DI;
        float v = (n < XROW) ? xp[(size_t)i * XROW * DI + (size_t)n * DI + k] : 0.f;
        xpbf[idx] = f2bf(v);
    }
}

// ---------------------------------------------------------------- fused KNN + patch-embed MLP: one block per (b,p)
__global__ __launch_bounds__(256) void k_knn_pe(
    const float* __restrict__ data,
    const float* __restrict__ w1, const float* __restrict__ b1,
    const float* __restrict__ g1, const float* __restrict__ be1,
    const float* __restrict__ w2, const float* __restrict__ b2,
    const float* __restrict__ g2, const float* __restrict__ be2,
    const unsigned short* __restrict__ w3bf, const float* __restrict__ b3,
    const float* __restrict__ g3, const float* __restrict__ be3,
    float* __restrict__ tokens, float* __restrict__ centers)
{
    const int bp = blockIdx.x;
    const int b = bp >> 6, p = bp & 63;
    const int tid = threadIdx.x;
    const int lane = tid & 63, wid = tid >> 6;
    const float* X = data + (size_t)b * NN * 3;
    const float inv_den = 0.99999500003749968752f; // 1/sqrt(1+1e-5)

    __shared__ unsigned long long wred[4];
    __shared__ int klist[KK];
    __shared__ float nxs[KK * 3];
    __shared__ float h1s[KK * 64];
    __shared__ short h2b[KK * 136];

    const float cx = X[p * 32 * 3 + 0];
    const float cy = X[p * 32 * 3 + 1];
    const float cz = X[p * 32 * 3 + 2];
    if (tid == 0) {
        centers[(b * PP + p) * 3 + 0] = cx;
        centers[(b * PP + p) * 3 + 1] = cy;
        centers[(b * PP + p) * 3 + 2] = cz;
    }

    // ---- KNN phase (packed u64 in registers)
    unsigned long long pk[8];
#pragma unroll
    for (int q = 0; q < 8; q++) {
        int i = tid + 256 * q;
        float dx = cx - X[i * 3 + 0];
        float dy = cy - X[i * 3 + 1];
        float dz = cz - X[i * 3 + 2];
        float d2 = dx * dx + dy * dy + dz * dz;
        pk[q] = ((unsigned long long)__float_as_uint(d2) << 32) | (unsigned)i;
    }
    for (int k = 0; k < KK; k++) {
        unsigned long long m = pk[0];
#pragma unroll
        for (int q = 1; q < 8; q++) m = pk[q] < m ? pk[q] : m;
#pragma unroll
        for (int off = 32; off; off >>= 1) {
            unsigned long long o = __shfl_xor(m, off);
            m = o < m ? o : m;
        }
        if (lane == 0) wred[wid] = m;
        __syncthreads();
        unsigned long long g = wred[0];
#pragma unroll
        for (int w = 1; w < 4; w++) g = wred[w] < g ? wred[w] : g;
#pragma unroll
        for (int q = 0; q < 8; q++)
            if (pk[q] == g) pk[q] = ~0ull;
        if (tid == 0) klist[k] = (int)(g & 0xffffffffu);
        __syncthreads();
    }

    // ---- patch MLP phase
    if (tid < KK) {
        int q = klist[tid];
        nxs[tid * 3 + 0] = X[q * 3 + 0] - cx;
        nxs[tid * 3 + 1] = X[q * 3 + 1] - cy;
        nxs[tid * 3 + 2] = X[q * 3 + 2] - cz;
    }
    __syncthreads();

    for (int e = tid; e < KK * 64; e += 256) {
        int j = e >> 6, c = e & 63;
        float v = nxs[j * 3 + 0] * w1[c * 3 + 0] + nxs[j * 3 + 1] * w1[c * 3 + 1] +
                  nxs[j * 3 + 2] * w1[c * 3 + 2] + b1[c];
        v = v * (g1[c] * inv_den) + be1[c];
        h1s[j * 64 + c] = gelu_exact(v);
    }
    __syncthreads();

    for (int e = tid; e < KK * 128; e += 256) {
        int j = e >> 7, c = e & 127;
        const float4* wr = (const float4*)(w2 + (size_t)c * 64);
        const float4* hr = (const float4*)(h1s + j * 64);
        float acc = 0.f;
#pragma unroll
        for (int q = 0; q < 16; q++) {
            float4 wv = wr[q], hv = hr[q];
            acc += hv.x * wv.x + hv.y * wv.y + hv.z * wv.z + hv.w * wv.w;
        }
        float v = (acc + b2[c]) * (g2[c] * inv_den) + be2[c];
        h2b[j * 136 + c] = (short)f2bf(gelu_exact(v));
    }
    __syncthreads();

    const int wave = tid >> 6;
    const int quad = lane >> 4, r = lane & 15;
    floatx4 acc3[2][6] = {};
#pragma unroll
    for (int ks = 0; ks < 4; ks++) {
        const int k0 = ks * 32;
        bf16x8 af[2];
        af[0] = *(const bf16x8*)(h2b + (size_t)r * 136 + quad * 8 + k0);
        af[1] = *(const bf16x8*)(h2b + (size_t)(16 + r) * 136 + quad * 8 + k0);
        bf16x8 bfv[6];
#pragma unroll
        for (int nj = 0; nj < 6; nj++) {
            int n = wave * 96 + nj * 16 + r;
            bfv[nj] = *(const bf16x8*)(w3bf + (size_t)n * 128 + quad * 8 + k0);
        }
#pragma unroll
        for (int mi = 0; mi < 2; mi++)
#pragma unroll
            for (int nj = 0; nj < 6; nj++)
                acc3[mi][nj] = __builtin_amdgcn_mfma_f32_16x16x32_bf16(af[mi], bfv[nj], acc3[mi][nj], 0, 0, 0);
    }
#pragma unroll
    for (int nj = 0; nj < 6; nj++) {
        int col = wave * 96 + nj * 16 + r;
        float sc = g3[col] * inv_den;
        float offc = b3[col] * sc + be3[col];
        float m = -3.4e38f;
#pragma unroll
        for (int mi = 0; mi < 2; mi++)
#pragma unroll
            for (int r2 = 0; r2 < 4; r2++)
                m = fmaxf(m, acc3[mi][nj][r2] * sc + offc);
        m = fmaxf(m, __shfl_xor(m, 16));
        m = fmaxf(m, __shfl_xor(m, 32));
        if (quad == 0) tokens[(size_t)bp * DD + col] = m;
    }
}

// ---------------------------------------------------------------- SFC orders
__global__ __launch_bounds__(64) void k_sfc(const float* __restrict__ centers,
                                            int* __restrict__ order_h,
                                            int* __restrict__ order_th)
{
    const int b = blockIdx.x;
    const int tid = threadIdx.x;
    float cc[3];
    cc[0] = centers[(b * PP + tid) * 3 + 0];
    cc[1] = centers[(b * PP + tid) * 3 + 1];
    cc[2] = centers[(b * PP + tid) * 3 + 2];

    __shared__ float csh[PP][3];
    __shared__ float slo[3], shi[3];
    csh[tid][0] = cc[0]; csh[tid][1] = cc[1]; csh[tid][2] = cc[2];
    __syncthreads();
    if (tid == 0) {
        for (int k = 0; k < 3; k++) {
            float lo = csh[0][k], hi = csh[0][k];
            for (int j = 1; j < PP; j++) { lo = fminf(lo, csh[j][k]); hi = fmaxf(hi, csh[j][k]); }
            slo[k] = lo; shi[k] = hi;
        }
    }
    __syncthreads();

    int q[3];
    for (int k = 0; k < 3; k++) {
        float t = (cc[k] - slo[k]) / (shi[k] - slo[k] + 1e-6f) * 1023.0f;
        int qi = (int)t;
        qi = qi < 0 ? 0 : (qi > 1023 ? 1023 : qi);
        q[k] = qi;
    }
    unsigned kh = spread_bits((unsigned)q[0]) | (spread_bits((unsigned)q[1]) << 1) |
                  (spread_bits((unsigned)q[2]) << 2);
    unsigned kt = spread_bits((unsigned)q[2]) | (spread_bits((unsigned)q[1]) << 1) |
                  (spread_bits((unsigned)q[0]) << 2);

    __shared__ unsigned khs[PP], kts[PP];
    khs[tid] = kh; kts[tid] = kt;
    __syncthreads();
    int rh = 0, rt = 0;
    for (int j = 0; j < PP; j++) {
        unsigned a = khs[j];
        rh += (a < kh) || (a == kh && j < tid);
        unsigned c = kts[j];
        rt += (c < kt) || (c == kt && j < tid);
    }
    order_h[b * PP + rh] = tid;
    order_th[b * PP + rt] = tid;
}

// ---------------------------------------------------------------- build token sequence
__global__ void k_build_t(const float* __restrict__ tokens,
                          const int* __restrict__ order_h, const int* __restrict__ order_th,
                          const float* __restrict__ hs, const float* __restrict__ hb,
                          const float* __restrict__ ts, const float* __restrict__ tb,
                          const float* __restrict__ pos, float* __restrict__ t)
{
    int idx = blockIdx.x * blockDim.x + threadIdx.x;
    if (idx >= BB * LL * DD) return;
    int d = idx % DD;
    int l = (idx / DD) % LL;
    int b = idx / (DD * LL);
    float v;
    if (l < PP) {
        int src = order_h[b * PP + l];
        v = tokens[((size_t)b * PP + src) * DD + d] * hs[d] + hb[d] + pos[l * DD + d];
    } else {
        int ll2 = l - PP;
        int src = order_th[b * PP + ll2];
        v = tokens[((size_t)b * PP + src) * DD + d] * ts[d] + tb[d] + pos[ll2 * DD + d];
    }
    t[idx] = v;
}

// ---------------------------------------------------------------- initial row moments (sum, sumsq) of t
__global__ __launch_bounds__(256) void k_rowstats(const float* __restrict__ t,
                                                  float* __restrict__ rowsum,
                                                  float* __restrict__ rowsumsq)
{
    const int tid = threadIdx.x;
    const int wid = tid >> 6, lane = tid & 63;
    const int row = blockIdx.x * 4 + wid;
    const float* xr = t + (size_t)row * DD;
    float s = 0.f, q = 0.f;
#pragma unroll
    for (int j = 0; j < 6; j++) { float v = xr[lane + 64 * j]; s += v; q += v * v; }
#pragma unroll
    for (int off = 32; off; off >>= 1) { s += __shfl_xor(s, off); q += __shfl_xor(q, off); }
    if (lane == 0) { rowsum[row] = s; rowsumsq[row] = q; }
}

// ---------------------------------------------------------------- xz MFMA GEMM with on-the-fly LN A-operand,
// fused conv/SiLU + fused xdbl partial.  grid (12, 8): y-block = one batch (128 tokens).
__global__ __launch_bounds__(256) void k_mfma_xz(
    const float* __restrict__ t,
    const float* __restrict__ rowsum, const float* __restrict__ rowsumsq,
    const float* __restrict__ ln_g, const float* __restrict__ ln_b,
    const unsigned short* __restrict__ inwbf,
    const float* __restrict__ cw, const float* __restrict__ cb,
    const unsigned short* __restrict__ xpbf,
    unsigned short* __restrict__ xcbf, unsigned short* __restrict__ zsbf,
    float* __restrict__ parts_x)
{
    __shared__ short ct[128][136];
    const int tid = threadIdx.x;
    const int wave = tid >> 6, lane = tid & 63;
    const int quad = lane >> 4, r = lane & 15;
    const int wm = wave >> 1, wn = wave & 1;
    const int b = blockIdx.y;
    const int n0 = blockIdx.x * 128;
    const int m0 = b * 128 + wm * 64;

    // per-row LN params for the 4 m-fragments this lane touches
    float mea[4], inv[4];
#pragma unroll
    for (int i = 0; i < 4; i++) {
        int row = m0 + i * 16 + r;
        float s = rowsum[row] * (1.0f / DD);
        float q = rowsumsq[row] * (1.0f / DD);
        float var = q - s * s;
        mea[i] = s;
        inv[i] = 1.0f / sqrtf(var + 1e-5f);
    }

    floatx4 acc[4][4] = {};
    const unsigned short* Bb = inwbf + (size_t)(n0 + wn * 64 + r) * DD + quad * 8;
    for (int k0 = 0; k0 < DD; k0 += 32) {
        const int kk = k0 + quad * 8;
        float4 gv0 = *(const float4*)(ln_g + kk);
        float4 gv1 = *(const float4*)(ln_g + kk + 4);
        float4 bv0 = *(const float4*)(ln_b + kk);
        float4 bv1 = *(const float4*)(ln_b + kk + 4);
        bf16x8 af[4], bfv[4];
#pragma unroll
        for (int i = 0; i < 4; i++) {
            const float* tp = t + (size_t)(m0 + i * 16 + r) * DD + kk;
            float4 t0 = *(const float4*)tp;
            float4 t1 = *(const float4*)(tp + 4);
            unsigned short a[8];
            a[0] = f2bf((t0.x - mea[i]) * inv[i] * gv0.x + bv0.x);
            a[1] = f2bf((t0.y - mea[i]) * inv[i] * gv0.y + bv0.y);
            a[2] = f2bf((t0.z - mea[i]) * inv[i] * gv0.z + bv0.z);
            a[3] = f2bf((t0.w - mea[i]) * inv[i] * gv0.w + bv0.w);
            a[4] = f2bf((t1.x - mea[i]) * inv[i] * gv1.x + bv1.x);
            a[5] = f2bf((t1.y - mea[i]) * inv[i] * gv1.y + bv1.y);
            a[6] = f2bf((t1.z - mea[i]) * inv[i] * gv1.z + bv1.z);
            a[7] = f2bf((t1.w - mea[i]) * inv[i] * gv1.w + bv1.w);
            af[i] = *(bf16x8*)a;
            bfv[i] = *(const bf16x8*)(Bb + (size_t)(i * 16) * DD + k0);
        }
#pragma unroll
        for (int i = 0; i < 4; i++)
#pragma unroll
            for (int j = 0; j < 4; j++)
                acc[i][j] = __builtin_amdgcn_mfma_f32_16x16x32_bf16(af[i], bfv[j], acc[i][j], 0, 0, 0);
    }

    // C -> LDS (bf16).  row = wm*64 + i*16 + quad*4 + r2, col = wn*64 + j*16 + r
#pragma unroll
    for (int i = 0; i < 4; i++)
#pragma unroll
        for (int r2 = 0; r2 < 4; r2++) {
            short* cp = &ct[wm * 64 + i * 16 + quad * 4 + r2][wn * 64 + r];
#pragma unroll
            for (int j = 0; j < 4; j++)
                cp[j * 16] = (short)f2bf(acc[i][j][r2]);
        }
    __syncthreads();

    const int l0 = (tid >> 4) * 8;
    const int c0 = (tid & 15) * 8;
    if (n0 < DI) {
        float cwv[8][4], cbv[8];
#pragma unroll
        for (int q = 0; q < 8; q++) {
            *(float4*)cwv[q] = *(const float4*)(cw + (size_t)(n0 + c0 + q) * 4);
            cbv[q] = cb[n0 + c0 + q];
        }
        unsigned short ov[8][8];
#pragma unroll
        for (int dl = 0; dl < 8; dl++) {
            const int l = l0 + dl;
            float u[8];
#pragma unroll
            for (int q = 0; q < 8; q++) u[q] = cbv[q];
#pragma unroll
            for (int j = 0; j < DCONV; j++) {
                int lt = l - (DCONV - 1) + j;
                if (lt >= 0) {
                    bf16x8 x = *(const bf16x8*)&ct[lt][c0];
#pragma unroll
                    for (int q = 0; q < 8; q++) u[q] += bf2f(x[q]) * cwv[q][j];
                }
            }
#pragma unroll
            for (int q = 0; q < 8; q++) ov[dl][q] = f2bf(siluf(u[q]));
        }
        __syncthreads();   // all pre-conv reads done
#pragma unroll
        for (int dl = 0; dl < 8; dl++) {
            const int l = l0 + dl;
            *(bf16x8*)&ct[l][c0] = *(bf16x8*)ov[dl];
            *(bf16x8*)(xcbf + (size_t)(b * LL + l) * DI + n0 + c0) = *(bf16x8*)ov[dl];
        }
        __syncthreads();

        // fused xdbl partial: wave handles rows wave*32..wave*32+31
        const int zi = blockIdx.x;   // 0..5
        floatx4 acc2[2][4] = {};
#pragma unroll
        for (int k0 = 0; k0 < 128; k0 += 32) {
            bf16x8 af2[2], bfv2[4];
#pragma unroll
            for (int i = 0; i < 2; i++)
                af2[i] = *(const bf16x8*)&ct[wave * 32 + i * 16 + r][k0 + quad * 8];
#pragma unroll
            for (int nj = 0; nj < 4; nj++)
                bfv2[nj] = *(const bf16x8*)(xpbf + (size_t)(nj * 16 + r) * DI + n0 + k0 + quad * 8);
#pragma unroll
            for (int i = 0; i < 2; i++)
#pragma unroll
                for (int nj = 0; nj < 4; nj++)
                    acc2[i][nj] = __builtin_amdgcn_mfma_f32_16x16x32_bf16(af2[i], bfv2[nj], acc2[i][nj], 0, 0, 0);
        }
        float* out = parts_x + (size_t)zi * NR * XROW;
#pragma unroll
        for (int i = 0; i < 2; i++)
#pragma unroll
            for (int nj = 0; nj < 4; nj++) {
                int col = nj * 16 + r;
                if (col < XROW) {
#pragma unroll
                    for (int r2 = 0; r2 < 4; r2++) {
                        int row = b * LL + wave * 32 + i * 16 + quad * 4 + r2;
                        out[(size_t)row * XROW + col] = acc2[i][nj][r2];
                    }
                }
            }
    } else {
        const int nz = n0 - DI;
#pragma unroll
        for (int dl = 0; dl < 8; dl++) {
            const int l = l0 + dl;
            bf16x8 x = *(const bf16x8*)&ct[l][c0];
            unsigned short o[8];
#pragma unroll
            for (int q = 0; q < 8; q++) o[q] = f2bf(siluf(bf2f(x[q])));
            *(bf16x8*)(zsbf + (size_t)(b * LL + l) * DI + nz + c0) = *(bf16x8*)o;
        }
    }
}

// ---------------------------------------------------------------- reduce xdbl partials + zero row-moment buffers
__global__ void k_xred(const float* __restrict__ parts, float* __restrict__ xdbl,
                       float* __restrict__ rowsum, float* __restrict__ rowsumsq)
{
    if (blockIdx.x == 0) {
        for (int j = threadIdx.x; j < NR; j += 256) { rowsum[j] = 0.f; rowsumsq[j] = 0.f; }
    }
    int i = blockIdx.x * 256 + threadIdx.x;
    if (i >= NR * XROW) return;
    float s = 0.f;
#pragma unroll
    for (int z = 0; z < XPARTS; z++) s += parts[(size_t)z * NR * XROW + i];
    xdbl[i] = s;
}

// ---------------------------------------------------------------- chunk-parallel selective scan (1 channel / 128-thr block)
__global__ __launch_bounds__(128) void k_scan(
    const float* __restrict__ xdbl,
    const unsigned short* __restrict__ xcbf, const unsigned short* __restrict__ zsbf,
    const float* __restrict__ dtw, const float* __restrict__ dtb,
    const float* __restrict__ Alog, const float* __restrict__ Dp,
    unsigned short* __restrict__ ybf)
{
    const int tid = threadIdx.x;
    const int b = blockIdx.x / DI;
    const int d = blockIdx.x % DI;

    __shared__ float da[LL][17];
    __shared__ float Bsh[LL][17];
    __shared__ float Csh[LL][17];
    __shared__ float dus[LL];
    __shared__ float us[LL];
    __shared__ float zs[LL];
    __shared__ float ApL[DS][9];
    __shared__ float HlL[DS][9];
    __shared__ float hst[DS][9];

    {
        const int t = tid;
        const size_t row = (size_t)b * LL + t;
        const float* xd = xdbl + row * XROW;
        const float* w = dtw + d * DTR;
        float acc = dtb[d];
#pragma unroll
        for (int k = 0; k < DTR; k++) acc += xd[k] * w[k];
        float delta = fmaxf(acc, 0.f) + log1pf(__expf(-fabsf(acc)));  // softplus
        float u = bf2f((short)xcbf[row * DI + d]);
        dus[t] = delta * u;
        us[t] = u;
        zs[t] = bf2f((short)zsbf[row * DI + d]);
#pragma unroll
        for (int s = 0; s < DS; s++) {
            da[t][s] = __expf(delta * (-__expf(Alog[d * DS + s])));
            Bsh[t][s] = xd[DTR + s];
            Csh[t][s] = xd[DTR + DS + s];
        }
    }
    __syncthreads();

    const int s = tid & 15;
    const int c = tid >> 4;           // chunk 0..7

    {
        float h = 0.f, Ap = 1.f;
#pragma unroll
        for (int q = 0; q < 16; q++) {
            int t = c * 16 + q;
            float a = da[t][s];
            h = h * a + dus[t] * Bsh[t][s];
            Ap *= a;
        }
        ApL[s][c] = Ap;
        HlL[s][c] = h;
    }
    __syncthreads();
    if (tid < DS) {
        float hs = 0.f;
#pragma unroll
        for (int cc = 0; cc < 8; cc++) {
            hst[tid][cc] = hs;
            hs = ApL[tid][cc] * hs + HlL[tid][cc];
        }
    }
    __syncthreads();

    {
        const float Dd = Dp[d];
        float h = hst[s][c];
        unsigned short* yc = ybf + ((size_t)b * LL + c * 16) * DI + d;
#pragma unroll
        for (int q = 0; q < 16; q++) {
            int t = c * 16 + q;
            float a = da[t][s];
            h = h * a + dus[t] * Bsh[t][s];
            float p = h * Csh[t][s];
            p += __shfl_xor(p, 1, 16);
            p += __shfl_xor(p, 2, 16);
            p += __shfl_xor(p, 4, 16);
            p += __shfl_xor(p, 8, 16);
            if (s == 0) yc[(size_t)q * DI] = f2bf((p + Dd * us[t]) * zs[t]);
        }
    }
}

// ---------------------------------------------------------------- out-proj MFMA GEMM, row-split, fused residual + row moments.
// grid (3, 32): x = 128-col tile, y = 32-row tile.  t[row,col] += (ybf @ ow^T), and
// per-row sum / sumsq of the NEW t accumulated into rowsum/rowsumsq (3 atomics/row each).
__global__ __launch_bounds__(256) void k_mfma_op(
    const unsigned short* __restrict__ ybf,
    const unsigned short* __restrict__ owbf,
    float* __restrict__ t,
    float* __restrict__ rowsum, float* __restrict__ rowsumsq)
{
    const int tid = threadIdx.x;
    const int wave = tid >> 6, lane = tid & 63;
    const int quad = lane >> 4, r = lane & 15;
    const int n0 = blockIdx.x * 128;
    const int m0 = blockIdx.y * 32;

    floatx4 acc[2][2] = {};
    const unsigned short* Ab = ybf + (size_t)(m0 + r) * DI + quad * 8;
    const unsigned short* Bb = owbf + (size_t)(n0 + wave * 32 + r) * DI + quad * 8;
    for (int k0 = 0; k0 < DI; k0 += 32) {
        bf16x8 af[2], bfv[2];
#pragma unroll
        for (int i = 0; i < 2; i++) {
            af[i] = *(const bf16x8*)(Ab + (size_t)(i * 16) * DI + k0);
            bfv[i] = *(const bf16x8*)(Bb + (size_t)(i * 16) * DI + k0);
        }
#pragma unroll
        for (int i = 0; i < 2; i++)
#pragma unroll
            for (int j = 0; j < 2; j++)
                acc[i][j] = __builtin_amdgcn_mfma_f32_16x16x32_bf16(af[i], bfv[j], acc[i][j], 0, 0, 0);
    }

    __shared__ float wsum[4][32], wsq[4][32];
#pragma unroll
    for (int mi = 0; mi < 2; mi++)
#pragma unroll
        for (int r2 = 0; r2 < 4; r2++) {
            const int row = m0 + mi * 16 + quad * 4 + r2;
            float s = 0.f, q = 0.f;
#pragma unroll
            for (int nj = 0; nj < 2; nj++) {
                int col = n0 + wave * 32 + nj * 16 + r;
                float* tp = t + (size_t)row * DD + col;
                float v = *tp + acc[mi][nj][r2];
                *tp = v;
                s += v; q += v * v;
            }
#pragma unroll
            for (int off = 1; off < 16; off <<= 1) {
                s += __shfl_xor(s, off, 16);
                q += __shfl_xor(q, off, 16);
            }
            if (r == 0) {
                wsum[wave][mi * 16 + quad * 4 + r2] = s;
                wsq[wave][mi * 16 + quad * 4 + r2] = q;
            }
        }
    __syncthreads();
    if (tid < 32) {
        float s = wsum[0][tid] + wsum[1][tid] + wsum[2][tid] + wsum[3][tid];
        float q = wsq[0][tid] + wsq[1][tid] + wsq[2][tid] + wsq[3][tid];
        atomicAdd(&rowsum[m0 + tid], s);
        atomicAdd(&rowsumsq[m0 + tid], q);
    }
}

// ---------------------------------------------------------------- head: final LN + mean-pool + 3-layer MLP, one block per batch
__global__ __launch_bounds__(256) void k_head(const float* __restrict__ t,
    const float* __restrict__ ng, const float* __restrict__ nb,
    const float* __restrict__ w1, const float* __restrict__ b1,
    const float* __restrict__ w2, const float* __restrict__ b2,
    const float* __restrict__ w3, const float* __restrict__ b3,
    float* __restrict__ out)
{
    const int b = blockIdx.x, tid = threadIdx.x;
    const int wave = tid >> 6, lane = tid & 63;
    __shared__ float pw[4][DD];
    __shared__ float pl[DD];
    __shared__ float h1[256];
    __shared__ float h2[64];

    for (int c = lane; c < DD; c += 64) pw[wave][c] = 0.f;
    __syncthreads();

    for (int rr = 0; rr < 32; rr++) {
        const int row = b * LL + wave * 32 + rr;
        const float* xr = t + (size_t)row * DD;
        float v[6];
        float s = 0.f, q = 0.f;
#pragma unroll
        for (int j = 0; j < 6; j++) { v[j] = xr[lane + 64 * j]; s += v[j]; q += v[j] * v[j]; }
#pragma unroll
        for (int off = 32; off; off >>= 1) { s += __shfl_xor(s, off); q += __shfl_xor(q, off); }
        float mean = s * (1.0f / DD);
        float var = q * (1.0f / DD) - mean * mean;
        float inv = 1.0f / sqrtf(var + 1e-5f);
#pragma unroll
        for (int j = 0; j < 6; j++) {
            int c = lane + 64 * j;
            pw[wave][c] += (v[j] - mean) * inv * ng[c] + nb[c];
        }
    }
    __syncthreads();
    for (int c = tid; c < DD; c += 256)
        pl[c] = (pw[0][c] + pw[1][c] + pw[2][c] + pw[3][c]) * (1.0f / LL);
    __syncthreads();

    {
        float acc = b1[tid];
        const float* wr = w1 + (size_t)tid * DD;
        for (int k = 0; k < DD; k++) acc += pl[k] * wr[k];
        h1[tid] = fmaxf(acc, 0.f);
    }
    __syncthreads();
    if (tid < 64) {
        float acc = b2[tid];
        const float* wr = w2 + (size_t)tid * 256;
        for (int k = 0; k < 256; k++) acc += h1[k] * wr[k];
        h2[tid] = fmaxf(acc, 0.f);
    }
    __syncthreads();
    if (tid < NC) {
        float acc = b3[tid];
        const float* wr = w3 + (size_t)tid * 64;
        for (int k = 0; k < 64; k++) acc += h2[k] * wr[k];
        out[b * NC + tid] = acc;
    }
}

// ---------------------------------------------------------------- launch
extern "C" void kernel_launch(void* const* d_in, const int* in_sizes, int n_in,
                              void* d_out, int out_size, void* d_ws, size_t ws_size,
                              hipStream_t stream)
{
    const float* data      = (const float*)d_in[0];
    const float* pe_w1     = (const float*)d_in[1];
    const float* pe_b1     = (const float*)d_in[2];
    const float* pe_g1     = (const float*)d_in[3];
    const float* pe_be1    = (const float*)d_in[4];
    const float* pe_w2     = (const float*)d_in[5];
    const float* pe_b2     = (const float*)d_in[6];
    const float* pe_g2     = (const float*)d_in[7];
    const float* pe_be2    = (const float*)d_in[8];
    const float* pe_w3     = (const float*)d_in[9];
    const float* pe_b3     = (const float*)d_in[10];
    const float* pe_g3     = (const float*)d_in[11];
    const float* pe_be3    = (const float*)d_in[12];
    const float* oi_h_scale  = (const float*)d_in[13];
    const float* oi_h_shift  = (const float*)d_in[14];
    const float* oi_th_scale = (const float*)d_in[15];
    const float* oi_th_shift = (const float*)d_in[16];
    const float* pos_embed = (const float*)d_in[17];
    const float* blk_ln_g  = (const float*)d_in[18];
    const float* blk_ln_b  = (const float*)d_in[19];
    const float* blk_in_w  = (const float*)d_in[20];
    const float* blk_conv_w = (const float*)d_in[21];
    const float* blk_conv_b = (const float*)d_in[22];
    const float* blk_xp_w  = (const float*)d_in[23];
    const float* blk_dt_w  = (const float*)d_in[24];
    const float* blk_dt_b  = (const float*)d_in[25];
    const float* blk_Alog  = (const float*)d_in[26];
    const float* blk_D     = (const float*)d_in[27];
    const float* blk_out_w = (const float*)d_in[28];
    const float* norm_g    = (const float*)d_in[29];
    const float* norm_b    = (const float*)d_in[30];
    const float* mlp_w1    = (const float*)d_in[31];
    const float* mlp_b1    = (const float*)d_in[32];
    const float* mlp_w2    = (const float*)d_in[33];
    const float* mlp_b2    = (const float*)d_in[34];
    const float* mlp_w3    = (const float*)d_in[35];
    const float* mlp_b3    = (const float*)d_in[36];

    float* ws = (float*)d_ws;
    size_t off = 0;
    auto alloc = [&](size_t n) { float* p = ws + off; off += (n + 63) & ~(size_t)63; return p; };
    float* tokens  = alloc((size_t)BB * PP * DD);
    float* centers = alloc((size_t)BB * PP * 3);
    int*   order_h = (int*)alloc((size_t)BB * PP);
    int*   order_th= (int*)alloc((size_t)BB * PP);
    float* t    = alloc((size_t)NR * DD);
    float* xdbl = alloc((size_t)NR * XROW);
    float* parts_x = alloc((size_t)XPARTS * NR * XROW);
    float* rowsum   = alloc(NR);
    float* rowsumsq = alloc(NR);
    unsigned short* xcbf  = (unsigned short*)alloc((size_t)NR * DI / 2);
    unsigned short* zsbf  = (unsigned short*)alloc((size_t)NR * DI / 2);
    unsigned short* ybf   = (unsigned short*)alloc((size_t)NR * DI / 2);
    unsigned short* inwbf = (unsigned short*)alloc((size_t)DEPTH * 2 * DI * DD / 2);
    unsigned short* owbf  = (unsigned short*)alloc((size_t)DEPTH * DD * DI / 2);
    unsigned short* xpbf  = (unsigned short*)alloc((size_t)DEPTH * 64 * DI / 2);
    unsigned short* w3bf  = (unsigned short*)alloc((size_t)DD * 128 / 2);

    // one-shot weight conversion (all four targets in one kernel)
    {
        const int total = DEPTH * 2 * DI * DD + DEPTH * DD * DI + DD * 128 + DEPTH * 64 * DI;
        k_cvt<<<(total + 255) / 256, 256, 0, stream>>>(
            blk_in_w, blk_out_w, pe_w3, blk_xp_w, inwbf, owbf, w3bf, xpbf);
    }

    k_knn_pe<<<BB * PP, 256, 0, stream>>>(data,
        pe_w1, pe_b1, pe_g1, pe_be1, pe_w2, pe_b2, pe_g2, pe_be2,
        w3bf, pe_b3, pe_g3, pe_be3, tokens, centers);
    k_sfc<<<BB, 64, 0, stream>>>(centers, order_h, order_th);
    {
        int nt = BB * LL * DD;
        k_build_t<<<(nt + 255) / 256, 256, 0, stream>>>(tokens, order_h, order_th,
            oi_h_scale, oi_h_shift, oi_th_scale, oi_th_shift, pos_embed, t);
    }
    k_rowstats<<<NR / 4, 256, 0, stream>>>(t, rowsum, rowsumsq);

    for (int i = 0; i < DEPTH; i++) {
        const float* ln_g = blk_ln_g + i * DD;
        const float* ln_b = blk_ln_b + i * DD;
        const float* cw   = blk_conv_w + (size_t)i * DI * DCONV;
        const float* cb   = blk_conv_b + (size_t)i * DI;
        const float* dtw  = blk_dt_w + (size_t)i * DI * DTR;
        const float* dtb  = blk_dt_b + (size_t)i * DI;
        const float* Al   = blk_Alog + (size_t)i * DI * DS;
        const float* Dpp  = blk_D + (size_t)i * DI;
        const unsigned short* inw = inwbf + (size_t)i * 2 * DI * DD;
        const unsigned short* ow  = owbf + (size_t)i * DD * DI;
        const unsigned short* xpb = xpbf + (size_t)i * 64 * DI;

        k_mfma_xz<<<dim3(12, BB), 256, 0, stream>>>(
            t, rowsum, rowsumsq, ln_g, ln_b, inw, cw, cb, xpb, xcbf, zsbf, parts_x);
        k_xred<<<(NR * XROW + 255) / 256, 256, 0, stream>>>(parts_x, xdbl, rowsum, rowsumsq);
        k_scan<<<BB * DI, 128, 0, stream>>>(xdbl, xcbf, zsbf, dtw, dtb, Al, Dpp, ybf);
        k_mfma_op<<<dim3(DD / 128, NR / 32), 256, 0, stream>>>(ybf, ow, t, rowsum, rowsumsq);
    }

    k_head<<<BB, 256, 0, stream>>>(t, norm_g, norm_b,
        mlp_w1, mlp_b1, mlp_w2, mlp_b2, mlp_w3, mlp_b3, (float*)d_out);
}

// Round 11
// 1064.338 us; speedup vs baseline: 1.2026x; 1.2026x over previous
//
#include <hip/hip_runtime.h>
#include <math.h>

#define BB 8
#define NN 2048
#define PP 64
#define KK 32
#define DD 384
#define DEPTH 12
#define DI 768
#define DS 16
#define DCONV 4
#define DTR 24
#define NC 40
#define LL 128  // 2*PP
#define XROW (DTR + 2 * DS)  // 56
#define NR (BB * LL)         // 1024
#define XPARTS 12            // xdbl split-K partials (fused into xz blocks, K=64 each)

using bf16x8 = __attribute__((ext_vector_type(8))) short;
using floatx4 = __attribute__((ext_vector_type(4))) float;

// ---------------------------------------------------------------- helpers
__device__ __forceinline__ float gelu_exact(float x) {
    return 0.5f * x * (1.0f + erff(x * 0.70710678118654752440f));
}
__device__ __forceinline__ float siluf(float x) {
    return x / (1.0f + expf(-x));
}
__device__ __forceinline__ unsigned short f2bf(float f) {
    unsigned u = __float_as_uint(f);
    u += 0x7fffu + ((u >> 16) & 1u);   // round-to-nearest-even
    return (unsigned short)(u >> 16);
}
__device__ __forceinline__ float bf2f(short s) {
    return __uint_as_float(((unsigned)(unsigned short)s) << 16);
}
__device__ __forceinline__ unsigned spread_bits(unsigned v) {
    v &= 1023u;
    v = (v | (v << 16)) & 50331903u;
    v = (v | (v << 8)) & 50393103u;
    v = (v | (v << 4)) & 51130563u;
    v = (v | (v << 2)) & 153391689u;
    return v;
}

// ---------------------------------------------------------------- one-shot weight conversions (all four)
__global__ void k_cvt(const float* __restrict__ in_w, const float* __restrict__ out_w,
                      const float* __restrict__ pe_w3, const float* __restrict__ xp,
                      unsigned short* __restrict__ inwbf, unsigned short* __restrict__ owbf,
                      unsigned short* __restrict__ w3bf, unsigned short* __restrict__ xpbf)
{
    int idx = blockIdx.x * 256 + threadIdx.x;
    const int n1 = DEPTH * 2 * DI * DD;
    const int n2 = DEPTH * DD * DI;
    const int n3 = DD * 128;
    const int n4 = DEPTH * 64 * DI;
    if (idx < n1) { inwbf[idx] = f2bf(in_w[idx]); return; }
    idx -= n1;
    if (idx < n2) { owbf[idx] = f2bf(out_w[idx]); return; }
    idx -= n2;
    if (idx < n3) { w3bf[idx] = f2bf(pe_w3[idx]); return; }
    idx -= n3;
    if (idx < n4) {
        int i = idx / (64 * DI);
        int rem = idx - i * 64 * DI;
        int n = rem / DI, k = rem % DI;
        float v = (n < XROW) ? xp[(size_t)i * XROW * DI + (size_t)n * DI + k] : 0.f;
        xpbf[idx] = f2bf(v);
    }
}

// ---------------------------------------------------------------- KNN: one block per (b,p)
__global__ __launch_bounds__(256) void k_knn(const float* __restrict__ data,
                                             int* __restrict__ knn_out,
                                             float* __restrict__ centers)
{
    const int bp = blockIdx.x;
    const int b = bp >> 6, p = bp & 63;
    const int tid = threadIdx.x;
    const int lane = tid & 63, wid = tid >> 6;
    const float* X = data + (size_t)b * NN * 3;

    const float cx = X[p * 32 * 3 + 0];
    const float cy = X[p * 32 * 3 + 1];
    const float cz = X[p * 32 * 3 + 2];
    if (tid == 0) {
        centers[(b * PP + p) * 3 + 0] = cx;
        centers[(b * PP + p) * 3 + 1] = cy;
        centers[(b * PP + p) * 3 + 2] = cz;
    }

    unsigned long long pk[8];
#pragma unroll
    for (int q = 0; q < 8; q++) {
        int i = tid + 256 * q;
        float dx = cx - X[i * 3 + 0];
        float dy = cy - X[i * 3 + 1];
        float dz = cz - X[i * 3 + 2];
        float d2 = dx * dx + dy * dy + dz * dz;
        pk[q] = ((unsigned long long)__float_as_uint(d2) << 32) | (unsigned)i;
    }

    __shared__ unsigned long long wred[4];
    __shared__ int klist[KK];
    for (int k = 0; k < KK; k++) {
        unsigned long long m = pk[0];
#pragma unroll
        for (int q = 1; q < 8; q++) m = pk[q] < m ? pk[q] : m;
#pragma unroll
        for (int off = 32; off; off >>= 1) {
            unsigned long long o = __shfl_xor(m, off);
            m = o < m ? o : m;
        }
        if (lane == 0) wred[wid] = m;
        __syncthreads();
        unsigned long long g = wred[0];
#pragma unroll
        for (int w = 1; w < 4; w++) g = wred[w] < g ? wred[w] : g;
#pragma unroll
        for (int q = 0; q < 8; q++)
            if (pk[q] == g) pk[q] = ~0ull;
        if (tid == 0) klist[k] = (int)(g & 0xffffffffu);
        __syncthreads();
    }
    if (tid < KK) knn_out[bp * KK + tid] = klist[tid];
}

// ---------------------------------------------------------------- patch-embed MLP: one block per (b,p)
__global__ __launch_bounds__(256) void k_pe_mlp(
    const float* __restrict__ data, const int* __restrict__ knn_in,
    const float* __restrict__ w1, const float* __restrict__ b1,
    const float* __restrict__ g1, const float* __restrict__ be1,
    const float* __restrict__ w2, const float* __restrict__ b2,
    const float* __restrict__ g2, const float* __restrict__ be2,
    const unsigned short* __restrict__ w3bf, const float* __restrict__ b3,
    const float* __restrict__ g3, const float* __restrict__ be3,
    float* __restrict__ tokens)
{
    const int bp = blockIdx.x;
    const int b = bp >> 6, p = bp & 63;
    const int tid = threadIdx.x;
    const float* X = data + (size_t)b * NN * 3;
    const float inv_den = 0.99999500003749968752f; // 1/sqrt(1+1e-5)

    __shared__ float nxs[KK * 3];
    __shared__ float h1s[KK * 64];
    __shared__ short h2b[KK * 136];

    const float cx = X[p * 32 * 3 + 0];
    const float cy = X[p * 32 * 3 + 1];
    const float cz = X[p * 32 * 3 + 2];
    if (tid < KK) {
        int q = knn_in[bp * KK + tid];
        nxs[tid * 3 + 0] = X[q * 3 + 0] - cx;
        nxs[tid * 3 + 1] = X[q * 3 + 1] - cy;
        nxs[tid * 3 + 2] = X[q * 3 + 2] - cz;
    }
    __syncthreads();

    for (int e = tid; e < KK * 64; e += 256) {
        int j = e >> 6, c = e & 63;
        float v = nxs[j * 3 + 0] * w1[c * 3 + 0] + nxs[j * 3 + 1] * w1[c * 3 + 1] +
                  nxs[j * 3 + 2] * w1[c * 3 + 2] + b1[c];
        v = v * (g1[c] * inv_den) + be1[c];
        h1s[j * 64 + c] = gelu_exact(v);
    }
    __syncthreads();

    for (int e = tid; e < KK * 128; e += 256) {
        int j = e >> 7, c = e & 127;
        const float4* wr = (const float4*)(w2 + (size_t)c * 64);
        const float4* hr = (const float4*)(h1s + j * 64);
        float acc = 0.f;
#pragma unroll
        for (int q = 0; q < 16; q++) {
            float4 wv = wr[q], hv = hr[q];
            acc += hv.x * wv.x + hv.y * wv.y + hv.z * wv.z + hv.w * wv.w;
        }
        float v = (acc + b2[c]) * (g2[c] * inv_den) + be2[c];
        h2b[j * 136 + c] = (short)f2bf(gelu_exact(v));
    }
    __syncthreads();

    const int wave = tid >> 6, lane = tid & 63;
    const int quad = lane >> 4, r = lane & 15;
    floatx4 acc3[2][6] = {};
#pragma unroll
    for (int ks = 0; ks < 4; ks++) {
        const int k0 = ks * 32;
        bf16x8 af[2];
        af[0] = *(const bf16x8*)(h2b + (size_t)r * 136 + quad * 8 + k0);
        af[1] = *(const bf16x8*)(h2b + (size_t)(16 + r) * 136 + quad * 8 + k0);
        bf16x8 bfv[6];
#pragma unroll
        for (int nj = 0; nj < 6; nj++) {
            int n = wave * 96 + nj * 16 + r;
            bfv[nj] = *(const bf16x8*)(w3bf + (size_t)n * 128 + quad * 8 + k0);
        }
#pragma unroll
        for (int mi = 0; mi < 2; mi++)
#pragma unroll
            for (int nj = 0; nj < 6; nj++)
                acc3[mi][nj] = __builtin_amdgcn_mfma_f32_16x16x32_bf16(af[mi], bfv[nj], acc3[mi][nj], 0, 0, 0);
    }
#pragma unroll
    for (int nj = 0; nj < 6; nj++) {
        int col = wave * 96 + nj * 16 + r;
        float sc = g3[col] * inv_den;
        float offc = b3[col] * sc + be3[col];
        float m = -3.4e38f;
#pragma unroll
        for (int mi = 0; mi < 2; mi++)
#pragma unroll
            for (int r2 = 0; r2 < 4; r2++)
                m = fmaxf(m, acc3[mi][nj][r2] * sc + offc);
        m = fmaxf(m, __shfl_xor(m, 16));
        m = fmaxf(m, __shfl_xor(m, 32));
        if (quad == 0) tokens[(size_t)bp * DD + col] = m;
    }
}

// ---------------------------------------------------------------- SFC orders
__global__ __launch_bounds__(64) void k_sfc(const float* __restrict__ centers,
                                            int* __restrict__ order_h,
                                            int* __restrict__ order_th)
{
    const int b = blockIdx.x;
    const int tid = threadIdx.x;
    float cc[3];
    cc[0] = centers[(b * PP + tid) * 3 + 0];
    cc[1] = centers[(b * PP + tid) * 3 + 1];
    cc[2] = centers[(b * PP + tid) * 3 + 2];

    __shared__ float csh[PP][3];
    __shared__ float slo[3], shi[3];
    csh[tid][0] = cc[0]; csh[tid][1] = cc[1]; csh[tid][2] = cc[2];
    __syncthreads();
    if (tid == 0) {
        for (int k = 0; k < 3; k++) {
            float lo = csh[0][k], hi = csh[0][k];
            for (int j = 1; j < PP; j++) { lo = fminf(lo, csh[j][k]); hi = fmaxf(hi, csh[j][k]); }
            slo[k] = lo; shi[k] = hi;
        }
    }
    __syncthreads();

    int q[3];
    for (int k = 0; k < 3; k++) {
        float t = (cc[k] - slo[k]) / (shi[k] - slo[k] + 1e-6f) * 1023.0f;
        int qi = (int)t;
        qi = qi < 0 ? 0 : (qi > 1023 ? 1023 : qi);
        q[k] = qi;
    }
    unsigned kh = spread_bits((unsigned)q[0]) | (spread_bits((unsigned)q[1]) << 1) |
                  (spread_bits((unsigned)q[2]) << 2);
    unsigned kt = spread_bits((unsigned)q[2]) | (spread_bits((unsigned)q[1]) << 1) |
                  (spread_bits((unsigned)q[0]) << 2);

    __shared__ unsigned khs[PP], kts[PP];
    khs[tid] = kh; kts[tid] = kt;
    __syncthreads();
    int rh = 0, rt = 0;
    for (int j = 0; j < PP; j++) {
        unsigned a = khs[j];
        rh += (a < kh) || (a == kh && j < tid);
        unsigned c = kts[j];
        rt += (c < kt) || (c == kt && j < tid);
    }
    order_h[b * PP + rh] = tid;
    order_th[b * PP + rt] = tid;
}

// ---------------------------------------------------------------- build token sequence
__global__ void k_build_t(const float* __restrict__ tokens,
                          const int* __restrict__ order_h, const int* __restrict__ order_th,
                          const float* __restrict__ hs, const float* __restrict__ hb,
                          const float* __restrict__ ts, const float* __restrict__ tb,
                          const float* __restrict__ pos, float* __restrict__ t)
{
    int idx = blockIdx.x * blockDim.x + threadIdx.x;
    if (idx >= BB * LL * DD) return;
    int d = idx % DD;
    int l = (idx / DD) % LL;
    int b = idx / (DD * LL);
    float v;
    if (l < PP) {
        int src = order_h[b * PP + l];
        v = tokens[((size_t)b * PP + src) * DD + d] * hs[d] + hb[d] + pos[l * DD + d];
    } else {
        int ll2 = l - PP;
        int src = order_th[b * PP + ll2];
        v = tokens[((size_t)b * PP + src) * DD + d] * ts[d] + tb[d] + pos[ll2 * DD + d];
    }
    t[idx] = v;
}

// ---------------------------------------------------------------- LN: t -> tbf (bf16), one wave per row
__global__ __launch_bounds__(256) void k_stats(const float* __restrict__ t,
                                               const float* __restrict__ g,
                                               const float* __restrict__ gb,
                                               unsigned short* __restrict__ tbf)
{
    const int tid = threadIdx.x;
    const int wid = tid >> 6, lane = tid & 63;
    const int row = blockIdx.x * 4 + wid;
    const size_t base = (size_t)row * DD;
    float v[6];
    float s = 0.f, q = 0.f;
#pragma unroll
    for (int j = 0; j < 6; j++) {
        v[j] = t[base + lane + 64 * j];
        s += v[j]; q += v[j] * v[j];
    }
#pragma unroll
    for (int off = 32; off; off >>= 1) { s += __shfl_xor(s, off); q += __shfl_xor(q, off); }
    float mean = s * (1.0f / DD);
    float var = q * (1.0f / DD) - mean * mean;
    float inv = 1.0f / sqrtf(var + 1e-5f);
#pragma unroll
    for (int j = 0; j < 6; j++) {
        int i = lane + 64 * j;
        tbf[base + i] = f2bf((v[j] - mean) * inv * g[i] + gb[i]);
    }
}

// ---------------------------------------------------------------- xz MFMA GEMM (128 tokens x 64 cols) + fused conv/SiLU
// + fused xdbl partial.  grid (24, 8): x = 64-col tile (12 xc + 12 z), y = batch.
__global__ __launch_bounds__(256) void k_mfma_xz(
    const unsigned short* __restrict__ tbf,
    const unsigned short* __restrict__ inwbf,
    const float* __restrict__ cw, const float* __restrict__ cb,
    const unsigned short* __restrict__ xpbf,
    unsigned short* __restrict__ xcbf, unsigned short* __restrict__ zsbf,
    float* __restrict__ parts_x)
{
    __shared__ short ct[128][72];   // 64 cols + 8 pad
    const int tid = threadIdx.x;
    const int wave = tid >> 6, lane = tid & 63;
    const int quad = lane >> 4, r = lane & 15;
    const int wm = wave >> 1, wn = wave & 1;
    const int b = blockIdx.y;
    const int n0 = blockIdx.x * 64;
    const int m0 = b * 128 + wm * 64;

    floatx4 acc[4][2] = {};
    const unsigned short* Ab = tbf + (size_t)(m0 + r) * DD + quad * 8;
    const unsigned short* Bb = inwbf + (size_t)(n0 + wn * 32 + r) * DD + quad * 8;
    for (int k0 = 0; k0 < DD; k0 += 32) {
        bf16x8 af[4], bfv[2];
#pragma unroll
        for (int i = 0; i < 4; i++)
            af[i] = *(const bf16x8*)(Ab + (size_t)(i * 16) * DD + k0);
#pragma unroll
        for (int j = 0; j < 2; j++)
            bfv[j] = *(const bf16x8*)(Bb + (size_t)(j * 16) * DD + k0);
#pragma unroll
        for (int i = 0; i < 4; i++)
#pragma unroll
            for (int j = 0; j < 2; j++)
                acc[i][j] = __builtin_amdgcn_mfma_f32_16x16x32_bf16(af[i], bfv[j], acc[i][j], 0, 0, 0);
    }

    // C -> LDS (bf16).  row = wm*64 + i*16 + quad*4 + r2, col = wn*32 + j*16 + r
#pragma unroll
    for (int i = 0; i < 4; i++)
#pragma unroll
        for (int r2 = 0; r2 < 4; r2++) {
            short* cp = &ct[wm * 64 + i * 16 + quad * 4 + r2][wn * 32 + r];
#pragma unroll
            for (int j = 0; j < 2; j++)
                cp[j * 16] = (short)f2bf(acc[i][j][r2]);
        }
    __syncthreads();

    const int l0 = (tid >> 3) * 4;      // 4 rows per thread
    const int c0 = (tid & 7) * 8;       // 8 cols per thread
    if (n0 < DI) {
        float cwv[8][4], cbv[8];
#pragma unroll
        for (int q = 0; q < 8; q++) {
            *(float4*)cwv[q] = *(const float4*)(cw + (size_t)(n0 + c0 + q) * 4);
            cbv[q] = cb[n0 + c0 + q];
        }
        unsigned short ov[4][8];
#pragma unroll
        for (int dl = 0; dl < 4; dl++) {
            const int l = l0 + dl;
            float u[8];
#pragma unroll
            for (int q = 0; q < 8; q++) u[q] = cbv[q];
#pragma unroll
            for (int j = 0; j < DCONV; j++) {
                int lt = l - (DCONV - 1) + j;
                if (lt >= 0) {
                    bf16x8 x = *(const bf16x8*)&ct[lt][c0];
#pragma unroll
                    for (int q = 0; q < 8; q++) u[q] += bf2f(x[q]) * cwv[q][j];
                }
            }
#pragma unroll
            for (int q = 0; q < 8; q++) ov[dl][q] = f2bf(siluf(u[q]));
        }
        __syncthreads();   // all pre-conv reads done
#pragma unroll
        for (int dl = 0; dl < 4; dl++) {
            const int l = l0 + dl;
            *(bf16x8*)&ct[l][c0] = *(bf16x8*)ov[dl];
            *(bf16x8*)(xcbf + (size_t)(b * LL + l) * DI + n0 + c0) = *(bf16x8*)ov[dl];
        }
        __syncthreads();

        // fused xdbl partial: K = 64 (this block's channel slice), 4 waves x 32 rows
        const int zi = blockIdx.x;   // 0..11
        floatx4 acc2[2][4] = {};
#pragma unroll
        for (int k0 = 0; k0 < 64; k0 += 32) {
            bf16x8 af2[2], bfv2[4];
#pragma unroll
            for (int i = 0; i < 2; i++)
                af2[i] = *(const bf16x8*)&ct[wave * 32 + i * 16 + r][k0 + quad * 8];
#pragma unroll
            for (int nj = 0; nj < 4; nj++)
                bfv2[nj] = *(const bf16x8*)(xpbf + (size_t)(nj * 16 + r) * DI + n0 + k0 + quad * 8);
#pragma unroll
            for (int i = 0; i < 2; i++)
#pragma unroll
                for (int nj = 0; nj < 4; nj++)
                    acc2[i][nj] = __builtin_amdgcn_mfma_f32_16x16x32_bf16(af2[i], bfv2[nj], acc2[i][nj], 0, 0, 0);
        }
        float* out = parts_x + (size_t)zi * NR * XROW;
#pragma unroll
        for (int i = 0; i < 2; i++)
#pragma unroll
            for (int nj = 0; nj < 4; nj++) {
                int col = nj * 16 + r;
                if (col < XROW) {
#pragma unroll
                    for (int r2 = 0; r2 < 4; r2++) {
                        int row = b * LL + wave * 32 + i * 16 + quad * 4 + r2;
                        out[(size_t)row * XROW + col] = acc2[i][nj][r2];
                    }
                }
            }
    } else {
        const int nz = n0 - DI;
#pragma unroll
        for (int dl = 0; dl < 4; dl++) {
            const int l = l0 + dl;
            bf16x8 x = *(const bf16x8*)&ct[l][c0];
            unsigned short o[8];
#pragma unroll
            for (int q = 0; q < 8; q++) o[q] = f2bf(siluf(bf2f(x[q])));
            *(bf16x8*)(zsbf + (size_t)(b * LL + l) * DI + nz + c0) = *(bf16x8*)o;
        }
    }
}

// ---------------------------------------------------------------- reduce xdbl partials (12)
__global__ void k_xred(const float* __restrict__ parts, float* __restrict__ xdbl)
{
    int i = blockIdx.x * 256 + threadIdx.x;
    if (i >= NR * XROW) return;
    float s = 0.f;
#pragma unroll
    for (int z = 0; z < XPARTS; z++) s += parts[(size_t)z * NR * XROW + i];
    xdbl[i] = s;
}

// ---------------------------------------------------------------- chunk-parallel selective scan (1 channel / 128-thr block)
__global__ __launch_bounds__(128) void k_scan(
    const float* __restrict__ xdbl,
    const unsigned short* __restrict__ xcbf, const unsigned short* __restrict__ zsbf,
    const float* __restrict__ dtw, const float* __restrict__ dtb,
    const float* __restrict__ Alog, const float* __restrict__ Dp,
    unsigned short* __restrict__ ybf)
{
    const int tid = threadIdx.x;
    const int b = blockIdx.x / DI;
    const int d = blockIdx.x % DI;

    __shared__ float da[LL][17];
    __shared__ float Bsh[LL][17];
    __shared__ float Csh[LL][17];
    __shared__ float dus[LL];
    __shared__ float us[LL];
    __shared__ float zs[LL];
    __shared__ float ApL[DS][9];
    __shared__ float HlL[DS][9];
    __shared__ float hst[DS][9];

    {
        const int t = tid;
        const size_t row = (size_t)b * LL + t;
        const float* xd = xdbl + row * XROW;
        const float* w = dtw + d * DTR;
        float acc = dtb[d];
#pragma unroll
        for (int k = 0; k < DTR; k++) acc += xd[k] * w[k];
        float delta = fmaxf(acc, 0.f) + log1pf(__expf(-fabsf(acc)));  // softplus
        float u = bf2f((short)xcbf[row * DI + d]);
        dus[t] = delta * u;
        us[t] = u;
        zs[t] = bf2f((short)zsbf[row * DI + d]);
#pragma unroll
        for (int s = 0; s < DS; s++) {
            da[t][s] = __expf(delta * (-__expf(Alog[d * DS + s])));
            Bsh[t][s] = xd[DTR + s];
            Csh[t][s] = xd[DTR + DS + s];
        }
    }
    __syncthreads();

    const int s = tid & 15;
    const int c = tid >> 4;           // chunk 0..7

    {
        float h = 0.f, Ap = 1.f;
#pragma unroll
        for (int q = 0; q < 16; q++) {
            int t = c * 16 + q;
            float a = da[t][s];
            h = h * a + dus[t] * Bsh[t][s];
            Ap *= a;
        }
        ApL[s][c] = Ap;
        HlL[s][c] = h;
    }
    __syncthreads();
    if (tid < DS) {
        float hs = 0.f;
#pragma unroll
        for (int cc = 0; cc < 8; cc++) {
            hst[tid][cc] = hs;
            hs = ApL[tid][cc] * hs + HlL[tid][cc];
        }
    }
    __syncthreads();

    {
        const float Dd = Dp[d];
        float h = hst[s][c];
        unsigned short* yc = ybf + ((size_t)b * LL + c * 16) * DI + d;
#pragma unroll
        for (int q = 0; q < 16; q++) {
            int t = c * 16 + q;
            float a = da[t][s];
            h = h * a + dus[t] * Bsh[t][s];
            float p = h * Csh[t][s];
            p += __shfl_xor(p, 1, 16);
            p += __shfl_xor(p, 2, 16);
            p += __shfl_xor(p, 4, 16);
            p += __shfl_xor(p, 8, 16);
            if (s == 0) yc[(size_t)q * DI] = f2bf((p + Dd * us[t]) * zs[t]);
        }
    }
}

// ---------------------------------------------------------------- out-proj MFMA GEMM, direct residual RMW on t.
// grid (6, 32): x = 64-col tile, y = 32-row tile.  K = 768.  Each t element touched once.
__global__ __launch_bounds__(256) void k_mfma_op(
    const unsigned short* __restrict__ ybf,
    const unsigned short* __restrict__ owbf,
    float* __restrict__ t)
{
    const int tid = threadIdx.x;
    const int wave = tid >> 6, lane = tid & 63;
    const int quad = lane >> 4, r = lane & 15;
    const int wr2 = wave >> 1, wc = wave & 1;
    const int n0 = blockIdx.x * 64 + wc * 32;
    const int m0 = blockIdx.y * 32 + wr2 * 16;

    floatx4 acc[2] = {};
    const unsigned short* Ab = ybf + (size_t)(m0 + r) * DI + quad * 8;
    const unsigned short* Bb = owbf + (size_t)(n0 + r) * DI + quad * 8;
    for (int k0 = 0; k0 < DI; k0 += 32) {
        bf16x8 af = *(const bf16x8*)(Ab + k0);
        bf16x8 b0 = *(const bf16x8*)(Bb + k0);
        bf16x8 b1 = *(const bf16x8*)(Bb + (size_t)16 * DI + k0);
        acc[0] = __builtin_amdgcn_mfma_f32_16x16x32_bf16(af, b0, acc[0], 0, 0, 0);
        acc[1] = __builtin_amdgcn_mfma_f32_16x16x32_bf16(af, b1, acc[1], 0, 0, 0);
    }

#pragma unroll
    for (int j = 0; j < 2; j++) {
        int col = n0 + j * 16 + r;
#pragma unroll
        for (int r2 = 0; r2 < 4; r2++) {
            int row = m0 + quad * 4 + r2;
            float* tp = t + (size_t)row * DD + col;
            *tp += acc[j][r2];
        }
    }
}

// ---------------------------------------------------------------- head: final LN + mean-pool + 3-layer MLP, one block per batch
__global__ __launch_bounds__(256) void k_head(const float* __restrict__ t,
    const float* __restrict__ ng, const float* __restrict__ nb,
    const float* __restrict__ w1, const float* __restrict__ b1,
    const float* __restrict__ w2, const float* __restrict__ b2,
    const float* __restrict__ w3, const float* __restrict__ b3,
    float* __restrict__ out)
{
    const int b = blockIdx.x, tid = threadIdx.x;
    const int wave = tid >> 6, lane = tid & 63;
    __shared__ float pw[4][DD];
    __shared__ float pl[DD];
    __shared__ float h1[256];
    __shared__ float h2[64];

    for (int c = lane; c < DD; c += 64) pw[wave][c] = 0.f;
    __syncthreads();

    for (int rr = 0; rr < 32; rr++) {
        const int row = b * LL + wave * 32 + rr;
        const float* xr = t + (size_t)row * DD;
        float v[6];
        float s = 0.f, q = 0.f;
#pragma unroll
        for (int j = 0; j < 6; j++) { v[j] = xr[lane + 64 * j]; s += v[j]; q += v[j] * v[j]; }
#pragma unroll
        for (int off = 32; off; off >>= 1) { s += __shfl_xor(s, off); q += __shfl_xor(q, off); }
        float mean = s * (1.0f / DD);
        float var = q * (1.0f / DD) - mean * mean;
        float inv = 1.0f / sqrtf(var + 1e-5f);
#pragma unroll
        for (int j = 0; j < 6; j++) {
            int c = lane + 64 * j;
            pw[wave][c] += (v[j] - mean) * inv * ng[c] + nb[c];
        }
    }
    __syncthreads();
    for (int c = tid; c < DD; c += 256)
        pl[c] = (pw[0][c] + pw[1][c] + pw[2][c] + pw[3][c]) * (1.0f / LL);
    __syncthreads();

    {
        float acc = b1[tid];
        const float* wr = w1 + (size_t)tid * DD;
        for (int k = 0; k < DD; k++) acc += pl[k] * wr[k];
        h1[tid] = fmaxf(acc, 0.f);
    }
    __syncthreads();
    if (tid < 64) {
        float acc = b2[tid];
        const float* wr = w2 + (size_t)tid * 256;
        for (int k = 0; k < 256; k++) acc += h1[k] * wr[k];
        h2[tid] = fmaxf(acc, 0.f);
    }
    __syncthreads();
    if (tid < NC) {
        float acc = b3[tid];
        const float* wr = w3 + (size_t)tid * 64;
        for (int k = 0; k < 64; k++) acc += h2[k] * wr[k];
        out[b * NC + tid] = acc;
    }
}

// ---------------------------------------------------------------- launch
extern "C" void kernel_launch(void* const* d_in, const int* in_sizes, int n_in,
                              void* d_out, int out_size, void* d_ws, size_t ws_size,
                              hipStream_t stream)
{
    const float* data      = (const float*)d_in[0];
    const float* pe_w1     = (const float*)d_in[1];
    const float* pe_b1     = (const float*)d_in[2];
    const float* pe_g1     = (const float*)d_in[3];
    const float* pe_be1    = (const float*)d_in[4];
    const float* pe_w2     = (const float*)d_in[5];
    const float* pe_b2     = (const float*)d_in[6];
    const float* pe_g2     = (const float*)d_in[7];
    const float* pe_be2    = (const float*)d_in[8];
    const float* pe_w3     = (const float*)d_in[9];
    const float* pe_b3     = (const float*)d_in[10];
    const float* pe_g3     = (const float*)d_in[11];
    const float* pe_be3    = (const float*)d_in[12];
    const float* oi_h_scale  = (const float*)d_in[13];
    const float* oi_h_shift  = (const float*)d_in[14];
    const float* oi_th_scale = (const float*)d_in[15];
    const float* oi_th_shift = (const float*)d_in[16];
    const float* pos_embed = (const float*)d_in[17];
    const float* blk_ln_g  = (const float*)d_in[18];
    const float* blk_ln_b  = (const float*)d_in[19];
    const float* blk_in_w  = (const float*)d_in[20];
    const float* blk_conv_w = (const float*)d_in[21];
    const float* blk_conv_b = (const float*)d_in[22];
    const float* blk_xp_w  = (const float*)d_in[23];
    const float* blk_dt_w  = (const float*)d_in[24];
    const float* blk_dt_b  = (const float*)d_in[25];
    const float* blk_Alog  = (const float*)d_in[26];
    const float* blk_D     = (const float*)d_in[27];
    const float* blk_out_w = (const float*)d_in[28];
    const float* norm_g    = (const float*)d_in[29];
    const float* norm_b    = (const float*)d_in[30];
    const float* mlp_w1    = (const float*)d_in[31];
    const float* mlp_b1    = (const float*)d_in[32];
    const float* mlp_w2    = (const float*)d_in[33];
    const float* mlp_b2    = (const float*)d_in[34];
    const float* mlp_w3    = (const float*)d_in[35];
    const float* mlp_b3    = (const float*)d_in[36];

    float* ws = (float*)d_ws;
    size_t off = 0;
    auto alloc = [&](size_t n) { float* p = ws + off; off += (n + 63) & ~(size_t)63; return p; };
    float* tokens  = alloc((size_t)BB * PP * DD);
    float* centers = alloc((size_t)BB * PP * 3);
    int*   order_h = (int*)alloc((size_t)BB * PP);
    int*   order_th= (int*)alloc((size_t)BB * PP);
    int*   knn_idx = (int*)alloc((size_t)BB * PP * KK);
    float* t    = alloc((size_t)NR * DD);
    float* xdbl = alloc((size_t)NR * XROW);
    float* parts_x = alloc((size_t)XPARTS * NR * XROW);
    unsigned short* tbf   = (unsigned short*)alloc((size_t)NR * DD / 2);
    unsigned short* xcbf  = (unsigned short*)alloc((size_t)NR * DI / 2);
    unsigned short* zsbf  = (unsigned short*)alloc((size_t)NR * DI / 2);
    unsigned short* ybf   = (unsigned short*)alloc((size_t)NR * DI / 2);
    unsigned short* inwbf = (unsigned short*)alloc((size_t)DEPTH * 2 * DI * DD / 2);
    unsigned short* owbf  = (unsigned short*)alloc((size_t)DEPTH * DD * DI / 2);
    unsigned short* xpbf  = (unsigned short*)alloc((size_t)DEPTH * 64 * DI / 2);
    unsigned short* w3bf  = (unsigned short*)alloc((size_t)DD * 128 / 2);

    // one-shot weight conversion (all four targets in one kernel)
    {
        const int total = DEPTH * 2 * DI * DD + DEPTH * DD * DI + DD * 128 + DEPTH * 64 * DI;
        k_cvt<<<(total + 255) / 256, 256, 0, stream>>>(
            blk_in_w, blk_out_w, pe_w3, blk_xp_w, inwbf, owbf, w3bf, xpbf);
    }

    k_knn<<<BB * PP, 256, 0, stream>>>(data, knn_idx, centers);
    k_pe_mlp<<<BB * PP, 256, 0, stream>>>(data, knn_idx,
        pe_w1, pe_b1, pe_g1, pe_be1, pe_w2, pe_b2, pe_g2, pe_be2,
        w3bf, pe_b3, pe_g3, pe_be3, tokens);
    k_sfc<<<BB, 64, 0, stream>>>(centers, order_h, order_th);
    {
        int nt = BB * LL * DD;
        k_build_t<<<(nt + 255) / 256, 256, 0, stream>>>(tokens, order_h, order_th,
            oi_h_scale, oi_h_shift, oi_th_scale, oi_th_shift, pos_embed, t);
    }

    for (int i = 0; i < DEPTH; i++) {
        const float* ln_g = blk_ln_g + i * DD;
        const float* ln_b = blk_ln_b + i * DD;
        const float* cw   = blk_conv_w + (size_t)i * DI * DCONV;
        const float* cb   = blk_conv_b + (size_t)i * DI;
        const float* dtw  = blk_dt_w + (size_t)i * DI * DTR;
        const float* dtb  = blk_dt_b + (size_t)i * DI;
        const float* Al   = blk_Alog + (size_t)i * DI * DS;
        const float* Dpp  = blk_D + (size_t)i * DI;
        const unsigned short* inw = inwbf + (size_t)i * 2 * DI * DD;
        const unsigned short* ow  = owbf + (size_t)i * DD * DI;
        const unsigned short* xpb = xpbf + (size_t)i * 64 * DI;

        k_stats<<<NR / 4, 256, 0, stream>>>(t, ln_g, ln_b, tbf);
        k_mfma_xz<<<dim3(24, BB), 256, 0, stream>>>(
            tbf, inw, cw, cb, xpb, xcbf, zsbf, parts_x);
        k_xred<<<(NR * XROW + 255) / 256, 256, 0, stream>>>(parts_x, xdbl);
        k_scan<<<BB * DI, 128, 0, stream>>>(xdbl, xcbf, zsbf, dtw, dtb, Al, Dpp, ybf);
        k_mfma_op<<<dim3(DD / 64, NR / 32), 256, 0, stream>>>(ybf, ow, t);
    }

    k_head<<<BB, 256, 0, stream>>>(t, norm_g, norm_b,
        mlp_w1, mlp_b1, mlp_w2, mlp_b2, mlp_w3, mlp_b3, (float*)d_out);
}

// Round 12
// 1042.959 us; speedup vs baseline: 1.2273x; 1.0205x over previous
//
#include <hip/hip_runtime.h>
#include <math.h>

#define BB 8
#define NN 2048
#define PP 64
#define KK 32
#define DD 384
#define DEPTH 12
#define DI 768
#define DS 16
#define DCONV 4
#define DTR 24
#define NC 40
#define LL 128  // 2*PP
#define XROW (DTR + 2 * DS)  // 56
#define NR (BB * LL)         // 1024
#define XPARTS 12            // xdbl split-K partials (fused into xz blocks, K=64 each)

using bf16x8 = __attribute__((ext_vector_type(8))) short;
using floatx4 = __attribute__((ext_vector_type(4))) float;

// ---------------------------------------------------------------- helpers
__device__ __forceinline__ float gelu_exact(float x) {
    return 0.5f * x * (1.0f + erff(x * 0.70710678118654752440f));
}
__device__ __forceinline__ float siluf(float x) {
    return x / (1.0f + expf(-x));
}
__device__ __forceinline__ unsigned short f2bf(float f) {
    unsigned u = __float_as_uint(f);
    u += 0x7fffu + ((u >> 16) & 1u);   // round-to-nearest-even
    return (unsigned short)(u >> 16);
}
__device__ __forceinline__ float bf2f(short s) {
    return __uint_as_float(((unsigned)(unsigned short)s) << 16);
}
__device__ __forceinline__ unsigned spread_bits(unsigned v) {
    v &= 1023u;
    v = (v | (v << 16)) & 50331903u;
    v = (v | (v << 8)) & 50393103u;
    v = (v | (v << 4)) & 51130563u;
    v = (v | (v << 2)) & 153391689u;
    return v;
}

// ---------------------------------------------------------------- one-shot weight conversions (all four)
__global__ void k_cvt(const float* __restrict__ in_w, const float* __restrict__ out_w,
                      const float* __restrict__ pe_w3, const float* __restrict__ xp,
                      unsigned short* __restrict__ inwbf, unsigned short* __restrict__ owbf,
                      unsigned short* __restrict__ w3bf, unsigned short* __restrict__ xpbf)
{
    int idx = blockIdx.x * 256 + threadIdx.x;
    const int n1 = DEPTH * 2 * DI * DD;
    const int n2 = DEPTH * DD * DI;
    const int n3 = DD * 128;
    const int n4 = DEPTH * 64 * DI;
    if (idx < n1) { inwbf[idx] = f2bf(in_w[idx]); return; }
    idx -= n1;
    if (idx < n2) { owbf[idx] = f2bf(out_w[idx]); return; }
    idx -= n2;
    if (idx < n3) { w3bf[idx] = f2bf(pe_w3[idx]); return; }
    idx -= n3;
    if (idx < n4) {
        int i = idx / (64 * DI);
        int rem = idx - i * 64 * DI;
        int n = rem / DI, k = rem % DI;
        float v = (n < XROW) ? xp[(size_t)i * XROW * DI + (size_t)n * DI + k] : 0.f;
        xpbf[idx] = f2bf(v);
    }
}

// ---------------------------------------------------------------- KNN: one block per (b,p)
__global__ __launch_bounds__(256) void k_knn(const float* __restrict__ data,
                                             int* __restrict__ knn_out,
                                             float* __restrict__ centers)
{
    const int bp = blockIdx.x;
    const int b = bp >> 6, p = bp & 63;
    const int tid = threadIdx.x;
    const int lane = tid & 63, wid = tid >> 6;
    const float* X = data + (size_t)b * NN * 3;

    const float cx = X[p * 32 * 3 + 0];
    const float cy = X[p * 32 * 3 + 1];
    const float cz = X[p * 32 * 3 + 2];
    if (tid == 0) {
        centers[(b * PP + p) * 3 + 0] = cx;
        centers[(b * PP + p) * 3 + 1] = cy;
        centers[(b * PP + p) * 3 + 2] = cz;
    }

    unsigned long long pk[8];
#pragma unroll
    for (int q = 0; q < 8; q++) {
        int i = tid + 256 * q;
        float dx = cx - X[i * 3 + 0];
        float dy = cy - X[i * 3 + 1];
        float dz = cz - X[i * 3 + 2];
        float d2 = dx * dx + dy * dy + dz * dz;
        pk[q] = ((unsigned long long)__float_as_uint(d2) << 32) | (unsigned)i;
    }

    __shared__ unsigned long long wred[4];
    __shared__ int klist[KK];
    for (int k = 0; k < KK; k++) {
        unsigned long long m = pk[0];
#pragma unroll
        for (int q = 1; q < 8; q++) m = pk[q] < m ? pk[q] : m;
#pragma unroll
        for (int off = 32; off; off >>= 1) {
            unsigned long long o = __shfl_xor(m, off);
            m = o < m ? o : m;
        }
        if (lane == 0) wred[wid] = m;
        __syncthreads();
        unsigned long long g = wred[0];
#pragma unroll
        for (int w = 1; w < 4; w++) g = wred[w] < g ? wred[w] : g;
#pragma unroll
        for (int q = 0; q < 8; q++)
            if (pk[q] == g) pk[q] = ~0ull;
        if (tid == 0) klist[k] = (int)(g & 0xffffffffu);
        __syncthreads();
    }
    if (tid < KK) knn_out[bp * KK + tid] = klist[tid];
}

// ---------------------------------------------------------------- patch-embed MLP: one block per (b,p)
__global__ __launch_bounds__(256) void k_pe_mlp(
    const float* __restrict__ data, const int* __restrict__ knn_in,
    const float* __restrict__ w1, const float* __restrict__ b1,
    const float* __restrict__ g1, const float* __restrict__ be1,
    const float* __restrict__ w2, const float* __restrict__ b2,
    const float* __restrict__ g2, const float* __restrict__ be2,
    const unsigned short* __restrict__ w3bf, const float* __restrict__ b3,
    const float* __restrict__ g3, const float* __restrict__ be3,
    float* __restrict__ tokens)
{
    const int bp = blockIdx.x;
    const int b = bp >> 6, p = bp & 63;
    const int tid = threadIdx.x;
    const float* X = data + (size_t)b * NN * 3;
    const float inv_den = 0.99999500003749968752f; // 1/sqrt(1+1e-5)

    __shared__ float nxs[KK * 3];
    __shared__ float h1s[KK * 64];
    __shared__ short h2b[KK * 136];

    const float cx = X[p * 32 * 3 + 0];
    const float cy = X[p * 32 * 3 + 1];
    const float cz = X[p * 32 * 3 + 2];
    if (tid < KK) {
        int q = knn_in[bp * KK + tid];
        nxs[tid * 3 + 0] = X[q * 3 + 0] - cx;
        nxs[tid * 3 + 1] = X[q * 3 + 1] - cy;
        nxs[tid * 3 + 2] = X[q * 3 + 2] - cz;
    }
    __syncthreads();

    for (int e = tid; e < KK * 64; e += 256) {
        int j = e >> 6, c = e & 63;
        float v = nxs[j * 3 + 0] * w1[c * 3 + 0] + nxs[j * 3 + 1] * w1[c * 3 + 1] +
                  nxs[j * 3 + 2] * w1[c * 3 + 2] + b1[c];
        v = v * (g1[c] * inv_den) + be1[c];
        h1s[j * 64 + c] = gelu_exact(v);
    }
    __syncthreads();

    for (int e = tid; e < KK * 128; e += 256) {
        int j = e >> 7, c = e & 127;
        const float4* wr = (const float4*)(w2 + (size_t)c * 64);
        const float4* hr = (const float4*)(h1s + j * 64);
        float acc = 0.f;
#pragma unroll
        for (int q = 0; q < 16; q++) {
            float4 wv = wr[q], hv = hr[q];
            acc += hv.x * wv.x + hv.y * wv.y + hv.z * wv.z + hv.w * wv.w;
        }
        float v = (acc + b2[c]) * (g2[c] * inv_den) + be2[c];
        h2b[j * 136 + c] = (short)f2bf(gelu_exact(v));
    }
    __syncthreads();

    const int wave = tid >> 6, lane = tid & 63;
    const int quad = lane >> 4, r = lane & 15;
    floatx4 acc3[2][6] = {};
#pragma unroll
    for (int ks = 0; ks < 4; ks++) {
        const int k0 = ks * 32;
        bf16x8 af[2];
        af[0] = *(const bf16x8*)(h2b + (size_t)r * 136 + quad * 8 + k0);
        af[1] = *(const bf16x8*)(h2b + (size_t)(16 + r) * 136 + quad * 8 + k0);
        bf16x8 bfv[6];
#pragma unroll
        for (int nj = 0; nj < 6; nj++) {
            int n = wave * 96 + nj * 16 + r;
            bfv[nj] = *(const bf16x8*)(w3bf + (size_t)n * 128 + quad * 8 + k0);
        }
#pragma unroll
        for (int mi = 0; mi < 2; mi++)
#pragma unroll
            for (int nj = 0; nj < 6; nj++)
                acc3[mi][nj] = __builtin_amdgcn_mfma_f32_16x16x32_bf16(af[mi], bfv[nj], acc3[mi][nj], 0, 0, 0);
    }
#pragma unroll
    for (int nj = 0; nj < 6; nj++) {
        int col = wave * 96 + nj * 16 + r;
        float sc = g3[col] * inv_den;
        float offc = b3[col] * sc + be3[col];
        float m = -3.4e38f;
#pragma unroll
        for (int mi = 0; mi < 2; mi++)
#pragma unroll
            for (int r2 = 0; r2 < 4; r2++)
                m = fmaxf(m, acc3[mi][nj][r2] * sc + offc);
        m = fmaxf(m, __shfl_xor(m, 16));
        m = fmaxf(m, __shfl_xor(m, 32));
        if (quad == 0) tokens[(size_t)bp * DD + col] = m;
    }
}

// ---------------------------------------------------------------- SFC orders
__global__ __launch_bounds__(64) void k_sfc(const float* __restrict__ centers,
                                            int* __restrict__ order_h,
                                            int* __restrict__ order_th)
{
    const int b = blockIdx.x;
    const int tid = threadIdx.x;
    float cc[3];
    cc[0] = centers[(b * PP + tid) * 3 + 0];
    cc[1] = centers[(b * PP + tid) * 3 + 1];
    cc[2] = centers[(b * PP + tid) * 3 + 2];

    __shared__ float csh[PP][3];
    __shared__ float slo[3], shi[3];
    csh[tid][0] = cc[0]; csh[tid][1] = cc[1]; csh[tid][2] = cc[2];
    __syncthreads();
    if (tid == 0) {
        for (int k = 0; k < 3; k++) {
            float lo = csh[0][k], hi = csh[0][k];
            for (int j = 1; j < PP; j++) { lo = fminf(lo, csh[j][k]); hi = fmaxf(hi, csh[j][k]); }
            slo[k] = lo; shi[k] = hi;
        }
    }
    __syncthreads();

    int q[3];
    for (int k = 0; k < 3; k++) {
        float t = (cc[k] - slo[k]) / (shi[k] - slo[k] + 1e-6f) * 1023.0f;
        int qi = (int)t;
        qi = qi < 0 ? 0 : (qi > 1023 ? 1023 : qi);
        q[k] = qi;
    }
    unsigned kh = spread_bits((unsigned)q[0]) | (spread_bits((unsigned)q[1]) << 1) |
                  (spread_bits((unsigned)q[2]) << 2);
    unsigned kt = spread_bits((unsigned)q[2]) | (spread_bits((unsigned)q[1]) << 1) |
                  (spread_bits((unsigned)q[0]) << 2);

    __shared__ unsigned khs[PP], kts[PP];
    khs[tid] = kh; kts[tid] = kt;
    __syncthreads();
    int rh = 0, rt = 0;
    for (int j = 0; j < PP; j++) {
        unsigned a = khs[j];
        rh += (a < kh) || (a == kh && j < tid);
        unsigned c = kts[j];
        rt += (c < kt) || (c == kt && j < tid);
    }
    order_h[b * PP + rh] = tid;
    order_th[b * PP + rt] = tid;
}

// ---------------------------------------------------------------- build token sequence
__global__ void k_build_t(const float* __restrict__ tokens,
                          const int* __restrict__ order_h, const int* __restrict__ order_th,
                          const float* __restrict__ hs, const float* __restrict__ hb,
                          const float* __restrict__ ts, const float* __restrict__ tb,
                          const float* __restrict__ pos, float* __restrict__ t)
{
    int idx = blockIdx.x * blockDim.x + threadIdx.x;
    if (idx >= BB * LL * DD) return;
    int d = idx % DD;
    int l = (idx / DD) % LL;
    int b = idx / (DD * LL);
    float v;
    if (l < PP) {
        int src = order_h[b * PP + l];
        v = tokens[((size_t)b * PP + src) * DD + d] * hs[d] + hb[d] + pos[l * DD + d];
    } else {
        int ll2 = l - PP;
        int src = order_th[b * PP + ll2];
        v = tokens[((size_t)b * PP + src) * DD + d] * ts[d] + tb[d] + pos[ll2 * DD + d];
    }
    t[idx] = v;
}

// ---------------------------------------------------------------- LN: t -> tbf (bf16), one wave per row
__global__ __launch_bounds__(256) void k_stats(const float* __restrict__ t,
                                               const float* __restrict__ g,
                                               const float* __restrict__ gb,
                                               unsigned short* __restrict__ tbf)
{
    const int tid = threadIdx.x;
    const int wid = tid >> 6, lane = tid & 63;
    const int row = blockIdx.x * 4 + wid;
    const size_t base = (size_t)row * DD;
    float v[6];
    float s = 0.f, q = 0.f;
#pragma unroll
    for (int j = 0; j < 6; j++) {
        v[j] = t[base + lane + 64 * j];
        s += v[j]; q += v[j] * v[j];
    }
#pragma unroll
    for (int off = 32; off; off >>= 1) { s += __shfl_xor(s, off); q += __shfl_xor(q, off); }
    float mean = s * (1.0f / DD);
    float var = q * (1.0f / DD) - mean * mean;
    float inv = 1.0f / sqrtf(var + 1e-5f);
#pragma unroll
    for (int j = 0; j < 6; j++) {
        int i = lane + 64 * j;
        tbf[base + i] = f2bf((v[j] - mean) * inv * g[i] + gb[i]);
    }
}

// ---------------------------------------------------------------- xz MFMA GEMM (128 tokens x 64 cols) + fused conv/SiLU
// + fused xdbl partial.  grid (24, 8): x = 64-col tile (12 xc + 12 z), y = batch.
__global__ __launch_bounds__(256) void k_mfma_xz(
    const unsigned short* __restrict__ tbf,
    const unsigned short* __restrict__ inwbf,
    const float* __restrict__ cw, const float* __restrict__ cb,
    const unsigned short* __restrict__ xpbf,
    unsigned short* __restrict__ xcbf, unsigned short* __restrict__ zsbf,
    float* __restrict__ parts_x)
{
    __shared__ short ct[128][72];   // 64 cols + 8 pad
    const int tid = threadIdx.x;
    const int wave = tid >> 6, lane = tid & 63;
    const int quad = lane >> 4, r = lane & 15;
    const int wm = wave >> 1, wn = wave & 1;
    const int b = blockIdx.y;
    const int n0 = blockIdx.x * 64;
    const int m0 = b * 128 + wm * 64;

    floatx4 acc[4][2] = {};
    const unsigned short* Ab = tbf + (size_t)(m0 + r) * DD + quad * 8;
    const unsigned short* Bb = inwbf + (size_t)(n0 + wn * 32 + r) * DD + quad * 8;
    for (int k0 = 0; k0 < DD; k0 += 32) {
        bf16x8 af[4], bfv[2];
#pragma unroll
        for (int i = 0; i < 4; i++)
            af[i] = *(const bf16x8*)(Ab + (size_t)(i * 16) * DD + k0);
#pragma unroll
        for (int j = 0; j < 2; j++)
            bfv[j] = *(const bf16x8*)(Bb + (size_t)(j * 16) * DD + k0);
#pragma unroll
        for (int i = 0; i < 4; i++)
#pragma unroll
            for (int j = 0; j < 2; j++)
                acc[i][j] = __builtin_amdgcn_mfma_f32_16x16x32_bf16(af[i], bfv[j], acc[i][j], 0, 0, 0);
    }

    // C -> LDS (bf16).  row = wm*64 + i*16 + quad*4 + r2, col = wn*32 + j*16 + r
#pragma unroll
    for (int i = 0; i < 4; i++)
#pragma unroll
        for (int r2 = 0; r2 < 4; r2++) {
            short* cp = &ct[wm * 64 + i * 16 + quad * 4 + r2][wn * 32 + r];
#pragma unroll
            for (int j = 0; j < 2; j++)
                cp[j * 16] = (short)f2bf(acc[i][j][r2]);
        }
    __syncthreads();

    const int l0 = (tid >> 3) * 4;      // 4 rows per thread
    const int c0 = (tid & 7) * 8;       // 8 cols per thread
    if (n0 < DI) {
        float cwv[8][4], cbv[8];
#pragma unroll
        for (int q = 0; q < 8; q++) {
            *(float4*)cwv[q] = *(const float4*)(cw + (size_t)(n0 + c0 + q) * 4);
            cbv[q] = cb[n0 + c0 + q];
        }
        unsigned short ov[4][8];
#pragma unroll
        for (int dl = 0; dl < 4; dl++) {
            const int l = l0 + dl;
            float u[8];
#pragma unroll
            for (int q = 0; q < 8; q++) u[q] = cbv[q];
#pragma unroll
            for (int j = 0; j < DCONV; j++) {
                int lt = l - (DCONV - 1) + j;
                if (lt >= 0) {
                    bf16x8 x = *(const bf16x8*)&ct[lt][c0];
#pragma unroll
                    for (int q = 0; q < 8; q++) u[q] += bf2f(x[q]) * cwv[q][j];
                }
            }
#pragma unroll
            for (int q = 0; q < 8; q++) ov[dl][q] = f2bf(siluf(u[q]));
        }
        __syncthreads();   // all pre-conv reads done
#pragma unroll
        for (int dl = 0; dl < 4; dl++) {
            const int l = l0 + dl;
            *(bf16x8*)&ct[l][c0] = *(bf16x8*)ov[dl];
            *(bf16x8*)(xcbf + (size_t)(b * LL + l) * DI + n0 + c0) = *(bf16x8*)ov[dl];
        }
        __syncthreads();

        // fused xdbl partial: K = 64 (this block's channel slice), 4 waves x 32 rows
        const int zi = blockIdx.x;   // 0..11
        floatx4 acc2[2][4] = {};
#pragma unroll
        for (int k0 = 0; k0 < 64; k0 += 32) {
            bf16x8 af2[2], bfv2[4];
#pragma unroll
            for (int i = 0; i < 2; i++)
                af2[i] = *(const bf16x8*)&ct[wave * 32 + i * 16 + r][k0 + quad * 8];
#pragma unroll
            for (int nj = 0; nj < 4; nj++)
                bfv2[nj] = *(const bf16x8*)(xpbf + (size_t)(nj * 16 + r) * DI + n0 + k0 + quad * 8);
#pragma unroll
            for (int i = 0; i < 2; i++)
#pragma unroll
                for (int nj = 0; nj < 4; nj++)
                    acc2[i][nj] = __builtin_amdgcn_mfma_f32_16x16x32_bf16(af2[i], bfv2[nj], acc2[i][nj], 0, 0, 0);
        }
        float* out = parts_x + (size_t)zi * NR * XROW;
#pragma unroll
        for (int i = 0; i < 2; i++)
#pragma unroll
            for (int nj = 0; nj < 4; nj++) {
                int col = nj * 16 + r;
                if (col < XROW) {
#pragma unroll
                    for (int r2 = 0; r2 < 4; r2++) {
                        int row = b * LL + wave * 32 + i * 16 + quad * 4 + r2;
                        out[(size_t)row * XROW + col] = acc2[i][nj][r2];
                    }
                }
            }
    } else {
        const int nz = n0 - DI;
#pragma unroll
        for (int dl = 0; dl < 4; dl++) {
            const int l = l0 + dl;
            bf16x8 x = *(const bf16x8*)&ct[l][c0];
            unsigned short o[8];
#pragma unroll
            for (int q = 0; q < 8; q++) o[q] = f2bf(siluf(bf2f(x[q])));
            *(bf16x8*)(zsbf + (size_t)(b * LL + l) * DI + nz + c0) = *(bf16x8*)o;
        }
    }
}

// ---------------------------------------------------------------- reduce xdbl partials (12)
__global__ void k_xred(const float* __restrict__ parts, float* __restrict__ xdbl)
{
    int i = blockIdx.x * 256 + threadIdx.x;
    if (i >= NR * XROW) return;
    float s = 0.f;
#pragma unroll
    for (int z = 0; z < XPARTS; z++) s += parts[(size_t)z * NR * XROW + i];
    xdbl[i] = s;
}

// ---------------------------------------------------------------- chunk-parallel selective scan (1 channel / 128-thr block)
__global__ __launch_bounds__(128) void k_scan(
    const float* __restrict__ xdbl,
    const unsigned short* __restrict__ xcbf, const unsigned short* __restrict__ zsbf,
    const float* __restrict__ dtw, const float* __restrict__ dtb,
    const float* __restrict__ Alog, const float* __restrict__ Dp,
    unsigned short* __restrict__ ybf)
{
    const int tid = threadIdx.x;
    const int b = blockIdx.x / DI;
    const int d = blockIdx.x % DI;

    __shared__ float da[LL][17];
    __shared__ float Bsh[LL][17];
    __shared__ float Csh[LL][17];
    __shared__ float dus[LL];
    __shared__ float us[LL];
    __shared__ float zs[LL];
    __shared__ float ApL[DS][9];
    __shared__ float HlL[DS][9];
    __shared__ float hst[DS][9];

    {
        const int t = tid;
        const size_t row = (size_t)b * LL + t;
        const float* xd = xdbl + row * XROW;
        const float* w = dtw + d * DTR;
        float acc = dtb[d];
#pragma unroll
        for (int k = 0; k < DTR; k++) acc += xd[k] * w[k];
        float delta = fmaxf(acc, 0.f) + log1pf(__expf(-fabsf(acc)));  // softplus
        float u = bf2f((short)xcbf[row * DI + d]);
        dus[t] = delta * u;
        us[t] = u;
        zs[t] = bf2f((short)zsbf[row * DI + d]);
#pragma unroll
        for (int s = 0; s < DS; s++) {
            da[t][s] = __expf(delta * (-__expf(Alog[d * DS + s])));
            Bsh[t][s] = xd[DTR + s];
            Csh[t][s] = xd[DTR + DS + s];
        }
    }
    __syncthreads();

    const int s = tid & 15;
    const int c = tid >> 4;           // chunk 0..7

    {
        float h = 0.f, Ap = 1.f;
#pragma unroll
        for (int q = 0; q < 16; q++) {
            int t = c * 16 + q;
            float a = da[t][s];
            h = h * a + dus[t] * Bsh[t][s];
            Ap *= a;
        }
        ApL[s][c] = Ap;
        HlL[s][c] = h;
    }
    __syncthreads();
    if (tid < DS) {
        float hs = 0.f;
#pragma unroll
        for (int cc = 0; cc < 8; cc++) {
            hst[tid][cc] = hs;
            hs = ApL[tid][cc] * hs + HlL[tid][cc];
        }
    }
    __syncthreads();

    {
        const float Dd = Dp[d];
        float h = hst[s][c];
        unsigned short* yc = ybf + ((size_t)b * LL + c * 16) * DI + d;
#pragma unroll
        for (int q = 0; q < 16; q++) {
            int t = c * 16 + q;
            float a = da[t][s];
            h = h * a + dus[t] * Bsh[t][s];
            float p = h * Csh[t][s];
            p += __shfl_xor(p, 1, 16);
            p += __shfl_xor(p, 2, 16);
            p += __shfl_xor(p, 4, 16);
            p += __shfl_xor(p, 8, 16);
            if (s == 0) yc[(size_t)q * DI] = f2bf((p + Dd * us[t]) * zs[t]);
        }
    }
}

// ---------------------------------------------------------------- out-proj MFMA GEMM, direct residual RMW on t.
// grid (6, 32): x = 64-col tile, y = 32-row tile.  K = 768.  Each t element touched once.
__global__ __launch_bounds__(256) void k_mfma_op(
    const unsigned short* __restrict__ ybf,
    const unsigned short* __restrict__ owbf,
    float* __restrict__ t)
{
    const int tid = threadIdx.x;
    const int wave = tid >> 6, lane = tid & 63;
    const int quad = lane >> 4, r = lane & 15;
    const int wr2 = wave >> 1, wc = wave & 1;
    const int n0 = blockIdx.x * 64 + wc * 32;
    const int m0 = blockIdx.y * 32 + wr2 * 16;

    floatx4 acc[2] = {};
    const unsigned short* Ab = ybf + (size_t)(m0 + r) * DI + quad * 8;
    const unsigned short* Bb = owbf + (size_t)(n0 + r) * DI + quad * 8;
    for (int k0 = 0; k0 < DI; k0 += 32) {
        bf16x8 af = *(const bf16x8*)(Ab + k0);
        bf16x8 b0 = *(const bf16x8*)(Bb + k0);
        bf16x8 b1 = *(const bf16x8*)(Bb + (size_t)16 * DI + k0);
        acc[0] = __builtin_amdgcn_mfma_f32_16x16x32_bf16(af, b0, acc[0], 0, 0, 0);
        acc[1] = __builtin_amdgcn_mfma_f32_16x16x32_bf16(af, b1, acc[1], 0, 0, 0);
    }

#pragma unroll
    for (int j = 0; j < 2; j++) {
        int col = n0 + j * 16 + r;
#pragma unroll
        for (int r2 = 0; r2 < 4; r2++) {
            int row = m0 + quad * 4 + r2;
            float* tp = t + (size_t)row * DD + col;
            *tp += acc[j][r2];
        }
    }
}

// ---------------------------------------------------------------- final LN + partial mean-pool: grid (8 chunks, 8 batches)
// each block LNs 16 rows of one batch and writes one partial pooled sum.
__global__ __launch_bounds__(256) void k_lnpool(const float* __restrict__ t,
                                                const float* __restrict__ ng,
                                                const float* __restrict__ nb,
                                                float* __restrict__ pparts)  // [BB][8][DD]
{
    const int b = blockIdx.y, chunk = blockIdx.x;
    const int tid = threadIdx.x;
    const int wave = tid >> 6, lane = tid & 63;
    __shared__ float pw[4][DD];

    for (int c = lane; c < DD; c += 64) pw[wave][c] = 0.f;
    __syncthreads();

    // each wave handles 4 rows of this 16-row chunk
    for (int rr = 0; rr < 4; rr++) {
        const int row = b * LL + chunk * 16 + wave * 4 + rr;
        const float* xr = t + (size_t)row * DD;
        float v[6];
        float s = 0.f, q = 0.f;
#pragma unroll
        for (int j = 0; j < 6; j++) { v[j] = xr[lane + 64 * j]; s += v[j]; q += v[j] * v[j]; }
#pragma unroll
        for (int off = 32; off; off >>= 1) { s += __shfl_xor(s, off); q += __shfl_xor(q, off); }
        float mean = s * (1.0f / DD);
        float var = q * (1.0f / DD) - mean * mean;
        float inv = 1.0f / sqrtf(var + 1e-5f);
#pragma unroll
        for (int j = 0; j < 6; j++) {
            int c = lane + 64 * j;
            pw[wave][c] += (v[j] - mean) * inv * ng[c] + nb[c];
        }
    }
    __syncthreads();
    float* out = pparts + ((size_t)b * 8 + chunk) * DD;
    for (int c = tid; c < DD; c += 256)
        out[c] = pw[0][c] + pw[1][c] + pw[2][c] + pw[3][c];
}

// ---------------------------------------------------------------- head MLP from pooled partials, one block per batch
__global__ __launch_bounds__(256) void k_mlp(const float* __restrict__ pparts,
    const float* __restrict__ w1, const float* __restrict__ b1,
    const float* __restrict__ w2, const float* __restrict__ b2,
    const float* __restrict__ w3, const float* __restrict__ b3,
    float* __restrict__ out)
{
    const int b = blockIdx.x, tid = threadIdx.x;
    __shared__ float pl[DD];
    __shared__ float h1[256];
    __shared__ float h2[64];
    for (int c = tid; c < DD; c += 256) {
        const float* pp = pparts + (size_t)b * 8 * DD + c;
        float s = 0.f;
#pragma unroll
        for (int z = 0; z < 8; z++) s += pp[z * DD];
        pl[c] = s * (1.0f / LL);
    }
    __syncthreads();

    {
        float acc = b1[tid];
        const float* wr = w1 + (size_t)tid * DD;
        for (int k = 0; k < DD; k++) acc += pl[k] * wr[k];
        h1[tid] = fmaxf(acc, 0.f);
    }
    __syncthreads();
    if (tid < 64) {
        float acc = b2[tid];
        const float* wr = w2 + (size_t)tid * 256;
        for (int k = 0; k < 256; k++) acc += h1[k] * wr[k];
        h2[tid] = fmaxf(acc, 0.f);
    }
    __syncthreads();
    if (tid < NC) {
        float acc = b3[tid];
        const float* wr = w3 + (size_t)tid * 64;
        for (int k = 0; k < 64; k++) acc += h2[k] * wr[k];
        out[b * NC + tid] = acc;
    }
}

// ---------------------------------------------------------------- launch
extern "C" void kernel_launch(void* const* d_in, const int* in_sizes, int n_in,
                              void* d_out, int out_size, void* d_ws, size_t ws_size,
                              hipStream_t stream)
{
    const float* data      = (const float*)d_in[0];
    const float* pe_w1     = (const float*)d_in[1];
    const float* pe_b1     = (const float*)d_in[2];
    const float* pe_g1     = (const float*)d_in[3];
    const float* pe_be1    = (const float*)d_in[4];
    const float* pe_w2     = (const float*)d_in[5];
    const float* pe_b2     = (const float*)d_in[6];
    const float* pe_g2     = (const float*)d_in[7];
    const float* pe_be2    = (const float*)d_in[8];
    const float* pe_w3     = (const float*)d_in[9];
    const float* pe_b3     = (const float*)d_in[10];
    const float* pe_g3     = (const float*)d_in[11];
    const float* pe_be3    = (const float*)d_in[12];
    const float* oi_h_scale  = (const float*)d_in[13];
    const float* oi_h_shift  = (const float*)d_in[14];
    const float* oi_th_scale = (const float*)d_in[15];
    const float* oi_th_shift = (const float*)d_in[16];
    const float* pos_embed = (const float*)d_in[17];
    const float* blk_ln_g  = (const float*)d_in[18];
    const float* blk_ln_b  = (const float*)d_in[19];
    const float* blk_in_w  = (const float*)d_in[20];
    const float* blk_conv_w = (const float*)d_in[21];
    const float* blk_conv_b = (const float*)d_in[22];
    const float* blk_xp_w  = (const float*)d_in[23];
    const float* blk_dt_w  = (const float*)d_in[24];
    const float* blk_dt_b  = (const float*)d_in[25];
    const float* blk_Alog  = (const float*)d_in[26];
    const float* blk_D     = (const float*)d_in[27];
    const float* blk_out_w = (const float*)d_in[28];
    const float* norm_g    = (const float*)d_in[29];
    const float* norm_b    = (const float*)d_in[30];
    const float* mlp_w1    = (const float*)d_in[31];
    const float* mlp_b1    = (const float*)d_in[32];
    const float* mlp_w2    = (const float*)d_in[33];
    const float* mlp_b2    = (const float*)d_in[34];
    const float* mlp_w3    = (const float*)d_in[35];
    const float* mlp_b3    = (const float*)d_in[36];

    float* ws = (float*)d_ws;
    size_t off = 0;
    auto alloc = [&](size_t n) { float* p = ws + off; off += (n + 63) & ~(size_t)63; return p; };
    float* tokens  = alloc((size_t)BB * PP * DD);
    float* centers = alloc((size_t)BB * PP * 3);
    int*   order_h = (int*)alloc((size_t)BB * PP);
    int*   order_th= (int*)alloc((size_t)BB * PP);
    int*   knn_idx = (int*)alloc((size_t)BB * PP * KK);
    float* t    = alloc((size_t)NR * DD);
    float* xdbl = alloc((size_t)NR * XROW);
    float* parts_x = alloc((size_t)XPARTS * NR * XROW);
    float* pparts  = alloc((size_t)BB * 8 * DD);
    unsigned short* tbf   = (unsigned short*)alloc((size_t)NR * DD / 2);
    unsigned short* xcbf  = (unsigned short*)alloc((size_t)NR * DI / 2);
    unsigned short* zsbf  = (unsigned short*)alloc((size_t)NR * DI / 2);
    unsigned short* ybf   = (unsigned short*)alloc((size_t)NR * DI / 2);
    unsigned short* inwbf = (unsigned short*)alloc((size_t)DEPTH * 2 * DI * DD / 2);
    unsigned short* owbf  = (unsigned short*)alloc((size_t)DEPTH * DD * DI / 2);
    unsigned short* xpbf  = (unsigned short*)alloc((size_t)DEPTH * 64 * DI / 2);
    unsigned short* w3bf  = (unsigned short*)alloc((size_t)DD * 128 / 2);

    // one-shot weight conversion (all four targets in one kernel)
    {
        const int total = DEPTH * 2 * DI * DD + DEPTH * DD * DI + DD * 128 + DEPTH * 64 * DI;
        k_cvt<<<(total + 255) / 256, 256, 0, stream>>>(
            blk_in_w, blk_out_w, pe_w3, blk_xp_w, inwbf, owbf, w3bf, xpbf);
    }

    k_knn<<<BB * PP, 256, 0, stream>>>(data, knn_idx, centers);
    k_pe_mlp<<<BB * PP, 256, 0, stream>>>(data, knn_idx,
        pe_w1, pe_b1, pe_g1, pe_be1, pe_w2, pe_b2, pe_g2, pe_be2,
        w3bf, pe_b3, pe_g3, pe_be3, tokens);
    k_sfc<<<BB, 64, 0, stream>>>(centers, order_h, order_th);
    {
        int nt = BB * LL * DD;
        k_build_t<<<(nt + 255) / 256, 256, 0, stream>>>(tokens, order_h, order_th,
            oi_h_scale, oi_h_shift, oi_th_scale, oi_th_shift, pos_embed, t);
    }

    for (int i = 0; i < DEPTH; i++) {
        const float* ln_g = blk_ln_g + i * DD;
        const float* ln_b = blk_ln_b + i * DD;
        const float* cw   = blk_conv_w + (size_t)i * DI * DCONV;
        const float* cb   = blk_conv_b + (size_t)i * DI;
        const float* dtw  = blk_dt_w + (size_t)i * DI * DTR;
        const float* dtb  = blk_dt_b + (size_t)i * DI;
        const float* Al   = blk_Alog + (size_t)i * DI * DS;
        const float* Dpp  = blk_D + (size_t)i * DI;
        const unsigned short* inw = inwbf + (size_t)i * 2 * DI * DD;
        const unsigned short* ow  = owbf + (size_t)i * DD * DI;
        const unsigned short* xpb = xpbf + (size_t)i * 64 * DI;

        k_stats<<<NR / 4, 256, 0, stream>>>(t, ln_g, ln_b, tbf);
        k_mfma_xz<<<dim3(24, BB), 256, 0, stream>>>(
            tbf, inw, cw, cb, xpb, xcbf, zsbf, parts_x);
        k_xred<<<(NR * XROW + 255) / 256, 256, 0, stream>>>(parts_x, xdbl);
        k_scan<<<BB * DI, 128, 0, stream>>>(xdbl, xcbf, zsbf, dtw, dtb, Al, Dpp, ybf);
        k_mfma_op<<<dim3(DD / 64, NR / 32), 256, 0, stream>>>(ybf, ow, t);
    }

    k_lnpool<<<dim3(8, BB), 256, 0, stream>>>(t, norm_g, norm_b, pparts);
    k_mlp<<<BB, 256, 0, stream>>>(pparts, mlp_w1, mlp_b1, mlp_w2, mlp_b2, mlp_w3, mlp_b3,
                                  (float*)d_out);
}